// Round 1
// baseline (1390.096 us; speedup 1.0000x reference)
//
#include <hip/hip_runtime.h>
#include <math.h>

#define B_  8
#define T_  4096
#define H_  512
#define FREQ 513
#define KP  528            // FREQ padded to multiple of 16
#define NFFT 1024
#define WINL 1024
#define HOP 256
#define PAD 384
#define OUTB 1048576       // per-batch output samples (cropped)
#define CLAMP_MAXV 100.0f

// ---------------- basis precompute ----------------
__global__ void basis_kernel(float* __restrict__ cosb, float* __restrict__ sinb) {
    int idx = blockIdx.x * 256 + threadIdx.x;
    if (idx >= NFFT * KP) return;
    int n = idx / KP, k = idx - n * KP;
    float c = 0.f, s = 0.f;
    if (k < FREQ) {
        int m = (n * k) & (NFFT - 1);          // exact periodic reduction
        float a = (float)m * 6.135923151542565e-3f; // 2*pi/1024
        float sc = ((k == 0) || (k == FREQ - 1)) ? (1.0f / NFFT) : (2.0f / NFFT);
        c = cosf(a) * sc;
        s = sinf(a) * sc;
    }
    cosb[idx] = c; sinb[idx] = s;
}

// ---------------- GEMM A: h = x@W + b, epilogue -> real/imag (b,f,t) ----------------
// grid: (64*bcount, 9); block 256. Tile 64(t) x 64(f-pairs), K=512.
__global__ __launch_bounds__(256) void gemm_a_kernel(
    const float* __restrict__ x, const float* __restrict__ W,
    const float* __restrict__ bias,
    float* __restrict__ realp, float* __restrict__ imagp, int b0)
{
    __shared__ float Xs[16][68];
    __shared__ float Wm[16][64];
    __shared__ float Wp[16][64];
    const int tid = threadIdx.x;
    const int tx = tid & 15;        // t sub-tile
    const int ty = tid >> 4;        // f sub-tile
    const int m0 = blockIdx.x * 64;               // row within this launch
    const int f0 = blockIdx.y * 64;

    float accM[4][4] = {{0.f}};
    float accP[4][4] = {{0.f}};

    const int lr  = tid >> 2;            // 0..63  (row for X load)
    const int lk  = (tid & 3) * 4;       // k sub for X load
    const int wc  = tid & 63;            // col for W load
    const int wk0 = (tid >> 6) * 4;      // k base for W load

    const size_t grow = (size_t)(b0 * T_ + m0);   // global x row base

    for (int k0 = 0; k0 < H_; k0 += 16) {
        float4 xv = *reinterpret_cast<const float4*>(&x[(grow + lr) * H_ + k0 + lk]);
        Xs[lk + 0][lr] = xv.x; Xs[lk + 1][lr] = xv.y;
        Xs[lk + 2][lr] = xv.z; Xs[lk + 3][lr] = xv.w;

        int f = f0 + wc;
        #pragma unroll
        for (int q = 0; q < 4; ++q) {
            int k = wk0 + q;
            float vm = 0.f, vp = 0.f;
            if (f < FREQ) {
                vm = W[(size_t)(k0 + k) * (2 * FREQ) + f];
                vp = W[(size_t)(k0 + k) * (2 * FREQ) + FREQ + f];
            }
            Wm[k][wc] = vm; Wp[k][wc] = vp;
        }
        __syncthreads();
        #pragma unroll
        for (int kk = 0; kk < 16; ++kk) {
            float4 xa = *reinterpret_cast<const float4*>(&Xs[kk][tx * 4]);
            float4 wm = *reinterpret_cast<const float4*>(&Wm[kk][ty * 4]);
            float4 wp = *reinterpret_cast<const float4*>(&Wp[kk][ty * 4]);
            float xr[4]  = {xa.x, xa.y, xa.z, xa.w};
            float wmr[4] = {wm.x, wm.y, wm.z, wm.w};
            float wpr[4] = {wp.x, wp.y, wp.z, wp.w};
            #pragma unroll
            for (int i = 0; i < 4; ++i)
                #pragma unroll
                for (int j = 0; j < 4; ++j) {
                    accM[i][j] = fmaf(xr[i], wmr[j], accM[i][j]);
                    accP[i][j] = fmaf(xr[i], wpr[j], accP[i][j]);
                }
        }
        __syncthreads();
    }

    const int b_local = m0 >> 12;                  // /4096 (batch-relative)
    const int tbase = (m0 & (T_ - 1)) + tx * 4;
    #pragma unroll
    for (int j = 0; j < 4; ++j) {
        int f = f0 + ty * 4 + j;
        if (f >= KP) continue;
        size_t rowoff = ((size_t)b_local * KP + f) * T_ + tbase;
        if (f < FREQ) {
            float bm = bias[f], bp = bias[FREQ + f];
            #pragma unroll
            for (int i = 0; i < 4; ++i) {
                float mag = fminf(expf(accM[i][j] + bm), CLAMP_MAXV);
                float ph = accP[i][j] + bp;
                float sp, cp;
                sincosf(ph, &sp, &cp);
                realp[rowoff + i] = mag * cp;
                imagp[rowoff + i] = mag * sp;
            }
        } else {
            // zero the K-padding rows (513..527) so GEMM B needs no bounds checks
            #pragma unroll
            for (int i = 0; i < 4; ++i) { realp[rowoff + i] = 0.f; imagp[rowoff + i] = 0.f; }
        }
    }
}

// ---------------- GEMM B: frames = (cosb@real - sinb@imag)*window, OLA into out ----------------
// grid: (64, 16, bcount); block 256. Tile 64(n) x 64(t), K=528.
__global__ __launch_bounds__(256) void gemm_b_kernel(
    const float* __restrict__ cosb, const float* __restrict__ sinb,
    const float* __restrict__ realp, const float* __restrict__ imagp,
    const float* __restrict__ window, float* __restrict__ out, int b0)
{
    __shared__ float Ac[16][68];
    __shared__ float As[16][68];
    __shared__ float Br[16][64];
    __shared__ float Bi[16][64];
    const int tid = threadIdx.x;
    const int tx = tid & 15;     // n sub-tile
    const int ty = tid >> 4;     // t sub-tile
    const int b_local = blockIdx.z;
    const int n0 = blockIdx.y * 64;
    const int t0 = blockIdx.x * 64;

    float acc[4][4] = {{0.f}};

    const int lr  = tid >> 2;
    const int lk  = (tid & 3) * 4;
    const int wc  = tid & 63;
    const int wk0 = (tid >> 6) * 4;

    for (int k0 = 0; k0 < KP; k0 += 16) {
        float4 vc = *reinterpret_cast<const float4*>(&cosb[(size_t)(n0 + lr) * KP + k0 + lk]);
        float4 vs = *reinterpret_cast<const float4*>(&sinb[(size_t)(n0 + lr) * KP + k0 + lk]);
        Ac[lk + 0][lr] = vc.x; Ac[lk + 1][lr] = vc.y;
        Ac[lk + 2][lr] = vc.z; Ac[lk + 3][lr] = vc.w;
        As[lk + 0][lr] = vs.x; As[lk + 1][lr] = vs.y;
        As[lk + 2][lr] = vs.z; As[lk + 3][lr] = vs.w;
        #pragma unroll
        for (int q = 0; q < 4; ++q) {
            int k = wk0 + q;
            size_t src = ((size_t)b_local * KP + k0 + k) * T_ + t0 + wc;
            Br[k][wc] = realp[src];
            Bi[k][wc] = imagp[src];
        }
        __syncthreads();
        #pragma unroll
        for (int kk = 0; kk < 16; ++kk) {
            float4 ac  = *reinterpret_cast<const float4*>(&Ac[kk][tx * 4]);
            float4 as_ = *reinterpret_cast<const float4*>(&As[kk][tx * 4]);
            float4 br  = *reinterpret_cast<const float4*>(&Br[kk][ty * 4]);
            float4 bi  = *reinterpret_cast<const float4*>(&Bi[kk][ty * 4]);
            float acr[4] = {ac.x, ac.y, ac.z, ac.w};
            float asr[4] = {as_.x, as_.y, as_.z, as_.w};
            float brr[4] = {br.x, br.y, br.z, br.w};
            float bir[4] = {bi.x, bi.y, bi.z, bi.w};
            #pragma unroll
            for (int i = 0; i < 4; ++i)
                #pragma unroll
                for (int j = 0; j < 4; ++j) {
                    acc[i][j] = fmaf(acr[i], brr[j], acc[i][j]);
                    acc[i][j] = fmaf(-asr[i], bir[j], acc[i][j]);
                }
        }
        __syncthreads();
    }

    float win[4];
    *reinterpret_cast<float4*>(win) =
        *reinterpret_cast<const float4*>(&window[n0 + tx * 4]);
    float* outb = out + (size_t)(b0 + b_local) * OUTB;
    #pragma unroll
    for (int j = 0; j < 4; ++j) {
        int t = t0 + ty * 4 + j;
        int sbase = t * HOP + n0 + tx * 4;
        #pragma unroll
        for (int i = 0; i < 4; ++i) {
            int o = sbase + i - PAD;
            if ((unsigned)o < (unsigned)OUTB)
                atomicAdd(&outb[o], acc[i][j] * win[i]);
        }
    }
}

// ---------------- finalize: divide by env ----------------
__global__ void finalize_kernel(const float* __restrict__ window, float* __restrict__ out) {
    int o = blockIdx.x * 256 + threadIdx.x;
    if (o >= OUTB) return;
    int s = o + PAD;
    int tlo = (s - (WINL - 1) + (HOP - 1)) >> 8;   // ceil((s-1023)/256)
    if (tlo < 0) tlo = 0;
    int thi = s >> 8; if (thi > T_ - 1) thi = T_ - 1;
    float e = 0.f;
    for (int t = tlo; t <= thi; ++t) {
        float w = window[s - (t << 8)];
        e += w * w;
    }
    float inv = 1.0f / (e + 1e-11f);
    #pragma unroll
    for (int b = 0; b < B_; ++b)
        out[(size_t)b * OUTB + o] *= inv;
}

// ---------------- launch ----------------
extern "C" void kernel_launch(void* const* d_in, const int* in_sizes, int n_in,
                              void* d_out, int out_size, void* d_ws, size_t ws_size,
                              hipStream_t stream) {
    const float* x      = (const float*)d_in[0];
    const float* W      = (const float*)d_in[1];
    const float* bias   = (const float*)d_in[2];
    const float* window = (const float*)d_in[3];
    float* out = (float*)d_out;
    float* ws  = (float*)d_ws;

    const size_t basis_f = (size_t)NFFT * KP;              // per basis
    const size_t spec_f_per_b = (size_t)KP * T_;           // per batch, per buffer

    // decide batching from ws_size (deterministic)
    int bcount = B_;
    {
        size_t need_full = (2 * basis_f + 2 * (size_t)B_ * spec_f_per_b) * sizeof(float);
        if (ws_size < need_full) bcount = 1;   // per-batch fallback (~22 MB)
    }

    float* cosb  = ws;
    float* sinb  = cosb + basis_f;
    float* realp = sinb + basis_f;
    float* imagp = realp + (size_t)bcount * spec_f_per_b;

    hipMemsetAsync(d_out, 0, (size_t)out_size * sizeof(float), stream);
    basis_kernel<<<(NFFT * KP + 255) / 256, 256, 0, stream>>>(cosb, sinb);

    for (int b0 = 0; b0 < B_; b0 += bcount) {
        dim3 ga(64 * bcount, 9);
        gemm_a_kernel<<<ga, 256, 0, stream>>>(x, W, bias, realp, imagp, b0);
        dim3 gb(64, 16, bcount);
        gemm_b_kernel<<<gb, 256, 0, stream>>>(cosb, sinb, realp, imagp, window, out, b0);
    }
    finalize_kernel<<<(OUTB + 255) / 256, 256, 0, stream>>>(window, out);
}

// Round 2
// 1155.155 us; speedup vs baseline: 1.2034x; 1.2034x over previous
//
#include <hip/hip_runtime.h>
#include <math.h>

#define B_  8
#define T_  4096
#define H_  512
#define FREQ 513
#define KP  528            // FREQ padded to 16
#define KB  1056           // 2*KP: [cos | -sin] concatenated along K
#define NFFT 1024
#define WINL 1024
#define HOP 256
#define PAD 384
#define OUTB 1048576       // per-batch output samples (cropped)
#define CLAMP_MAXV 100.0f

typedef __attribute__((ext_vector_type(8))) short bf16x8;
typedef __attribute__((ext_vector_type(4))) float f32x4;

__device__ inline ushort f2bf(float v) {
    union { float f; unsigned u; } x; x.f = v;
    unsigned r = x.u + 0x7FFFu + ((x.u >> 16) & 1u);   // RNE
    return (ushort)(r >> 16);
}
__device__ inline float bf2f(ushort h) {
    union { unsigned u; float f; } x; x.u = ((unsigned)h) << 16;
    return x.f;
}

#define GLOAD_LDS16(g, l) __builtin_amdgcn_global_load_lds( \
    (const __attribute__((address_space(1))) unsigned int*)(g), \
    (__attribute__((address_space(3))) unsigned int*)(l), 16, 0, 0)

// ---------------- basis precompute: A = [cos*scale | -sin*scale], split hi/lo bf16 ----------------
__global__ void basis_kernel(ushort* __restrict__ Ah, ushort* __restrict__ Al) {
    int idx = blockIdx.x * 256 + threadIdx.x;
    if (idx >= NFFT * KB) return;
    int n = idx / KB, k = idx - n * KB;
    float v = 0.f;
    int kk = (k < KP) ? k : (k - KP);
    if (kk < FREQ) {
        int m = (n * kk) & (NFFT - 1);
        float a = (float)m * 6.135923151542565e-3f;       // 2*pi/1024
        float sc = ((kk == 0) || (kk == FREQ - 1)) ? (1.0f / NFFT) : (2.0f / NFFT);
        v = (k < KP) ? (cosf(a) * sc) : (-sinf(a) * sc);
    }
    ushort h = f2bf(v);
    Ah[idx] = h;
    Al[idx] = f2bf(v - bf2f(h));
}

// ---------------- GEMM A: h = x@W + b (fp32), epilogue -> spec hi/lo bf16 at [t][k] ----------------
// grid: (64*bcount, 9); block 256.
__global__ __launch_bounds__(256) void gemm_a_kernel(
    const float* __restrict__ x, const float* __restrict__ W,
    const float* __restrict__ bias,
    ushort* __restrict__ Bh, ushort* __restrict__ Bl, int b0)
{
    __shared__ float Xs[16][68];
    __shared__ float Wm[16][64];
    __shared__ float Wp[16][64];
    const int tid = threadIdx.x;
    const int tx = tid & 15;        // t sub-tile
    const int ty = tid >> 4;        // f sub-tile
    const int m0 = blockIdx.x * 64;
    const int f0 = blockIdx.y * 64;

    float accM[4][4] = {{0.f}};
    float accP[4][4] = {{0.f}};

    const int lr  = tid >> 2;
    const int lk  = (tid & 3) * 4;
    const int wc  = tid & 63;
    const int wk0 = (tid >> 6) * 4;

    const size_t grow = (size_t)(b0 * T_ + m0);

    for (int k0 = 0; k0 < H_; k0 += 16) {
        float4 xv = *reinterpret_cast<const float4*>(&x[(grow + lr) * H_ + k0 + lk]);
        Xs[lk + 0][lr] = xv.x; Xs[lk + 1][lr] = xv.y;
        Xs[lk + 2][lr] = xv.z; Xs[lk + 3][lr] = xv.w;

        int f = f0 + wc;
        #pragma unroll
        for (int q = 0; q < 4; ++q) {
            int k = wk0 + q;
            float vm = 0.f, vp = 0.f;
            if (f < FREQ) {
                vm = W[(size_t)(k0 + k) * (2 * FREQ) + f];
                vp = W[(size_t)(k0 + k) * (2 * FREQ) + FREQ + f];
            }
            Wm[k][wc] = vm; Wp[k][wc] = vp;
        }
        __syncthreads();
        #pragma unroll
        for (int kk = 0; kk < 16; ++kk) {
            float4 xa = *reinterpret_cast<const float4*>(&Xs[kk][tx * 4]);
            float4 wm = *reinterpret_cast<const float4*>(&Wm[kk][ty * 4]);
            float4 wp = *reinterpret_cast<const float4*>(&Wp[kk][ty * 4]);
            float xr[4]  = {xa.x, xa.y, xa.z, xa.w};
            float wmr[4] = {wm.x, wm.y, wm.z, wm.w};
            float wpr[4] = {wp.x, wp.y, wp.z, wp.w};
            #pragma unroll
            for (int i = 0; i < 4; ++i)
                #pragma unroll
                for (int j = 0; j < 4; ++j) {
                    accM[i][j] = fmaf(xr[i], wmr[j], accM[i][j]);
                    accP[i][j] = fmaf(xr[i], wpr[j], accP[i][j]);
                }
        }
        __syncthreads();
    }

    // epilogue: nonlinearity + hi/lo bf16 split, layout [t][k] (k contiguous)
    const int b_local = m0 >> 12;
    const int tbase = (m0 & (T_ - 1)) + tx * 4;
    const int fb = f0 + ty * 4;
    if (fb >= KP) return;
    ushort* Bh_b = Bh + (size_t)b_local * T_ * KB;
    ushort* Bl_b = Bl + (size_t)b_local * T_ * KB;

    #pragma unroll
    for (int i = 0; i < 4; ++i) {
        int t = tbase + i;
        ushort rh[4], rl[4], ih[4], il[4];
        #pragma unroll
        for (int j = 0; j < 4; ++j) {
            int f = fb + j;
            float re = 0.f, im = 0.f;
            if (f < FREQ) {
                float mag = fminf(expf(accM[i][j] + bias[f]), CLAMP_MAXV);
                float ph = accP[i][j] + bias[FREQ + f];
                float sp, cp;
                sincosf(ph, &sp, &cp);
                re = mag * cp; im = mag * sp;
            }
            ushort h1 = f2bf(re); rh[j] = h1; rl[j] = f2bf(re - bf2f(h1));
            ushort h2 = f2bf(im); ih[j] = h2; il[j] = f2bf(im - bf2f(h2));
        }
        size_t row = (size_t)t * KB;
        *reinterpret_cast<ushort4*>(&Bh_b[row + fb])      = make_ushort4(rh[0], rh[1], rh[2], rh[3]);
        *reinterpret_cast<ushort4*>(&Bl_b[row + fb])      = make_ushort4(rl[0], rl[1], rl[2], rl[3]);
        *reinterpret_cast<ushort4*>(&Bh_b[row + KP + fb]) = make_ushort4(ih[0], ih[1], ih[2], ih[3]);
        *reinterpret_cast<ushort4*>(&Bl_b[row + KP + fb]) = make_ushort4(il[0], il[1], il[2], il[3]);
    }
}

// ---------------- GEMM B (MFMA): frames = A@spec, *window, OLA into out ----------------
// grid: (32 t-tiles, 8 n-tiles, bcount); block 256 (4 waves, 2x2).
__global__ __launch_bounds__(256) void gemm_b_mfma(
    const ushort* __restrict__ Ah, const ushort* __restrict__ Al,
    const ushort* __restrict__ Bh, const ushort* __restrict__ Bl,
    const float* __restrict__ window, float* __restrict__ out, int b0)
{
    __shared__ __attribute__((aligned(16))) ushort Asb[128 * 32];
    __shared__ __attribute__((aligned(16))) ushort Bsb[128 * 32];
    const int tid = threadIdx.x;
    const int lane = tid & 63;
    const int w = tid >> 6;
    const int wr = w >> 1, wc = w & 1;
    const int b_local = blockIdx.z;
    const int n0 = blockIdx.y * 128;
    const int t0 = blockIdx.x * 128;

    const ushort* Bh_b = Bh + (size_t)b_local * T_ * KB;
    const ushort* Bl_b = Bl + (size_t)b_local * T_ * KB;

    f32x4 acc[4][4] = {};

    const int srow = tid >> 2;           // staging row 0..63 (per pass)
    const int selem = (tid & 3) * 8;     // staging k-elem offset
    const int arow = lane & 15;
    const int kch = (lane >> 4) * 8;

    char* AsbB = (char*)Asb;
    char* BsbB = (char*)Bsb;
    const int ldsbase = w * 1024;        // wave-uniform within wave

    #pragma unroll
    for (int part = 0; part < 3; ++part) {
        const ushort* Ap = (part == 2) ? Al : Ah;
        const ushort* Bp = (part == 1) ? Bl_b : Bh_b;
        for (int k0 = 0; k0 < KB; k0 += 32) {
            #pragma unroll
            for (int q = 0; q < 2; ++q) {
                const ushort* ga = Ap + (size_t)(n0 + q * 64 + srow) * KB + k0 + selem;
                GLOAD_LDS16(ga, AsbB + q * 4096 + ldsbase);
                const ushort* gb = Bp + (size_t)(t0 + q * 64 + srow) * KB + k0 + selem;
                GLOAD_LDS16(gb, BsbB + q * 4096 + ldsbase);
            }
            __syncthreads();
            bf16x8 a[4], b[4];
            #pragma unroll
            for (int i = 0; i < 4; ++i)
                a[i] = *reinterpret_cast<const bf16x8*>(&Asb[(wr * 64 + i * 16 + arow) * 32 + kch]);
            #pragma unroll
            for (int j = 0; j < 4; ++j)
                b[j] = *reinterpret_cast<const bf16x8*>(&Bsb[(wc * 64 + j * 16 + arow) * 32 + kch]);
            #pragma unroll
            for (int i = 0; i < 4; ++i)
                #pragma unroll
                for (int j = 0; j < 4; ++j)
                    acc[i][j] = __builtin_amdgcn_mfma_f32_16x16x32_bf16(a[i], b[j], acc[i][j], 0, 0, 0);
            __syncthreads();
        }
    }

    // epilogue: D row = n, col = t; out[t*HOP + n - PAD] += D*window[n]
    const int crow = (lane >> 4) * 4;
    const int ccol = lane & 15;
    float* outb = out + (size_t)(b0 + b_local) * OUTB;
    #pragma unroll
    for (int i = 0; i < 4; ++i) {
        int nbase = n0 + wr * 64 + i * 16 + crow;
        float4 wv = *reinterpret_cast<const float4*>(&window[nbase]);
        float wr4[4] = {wv.x, wv.y, wv.z, wv.w};
        #pragma unroll
        for (int j = 0; j < 4; ++j) {
            int t = t0 + wc * 64 + j * 16 + ccol;
            int sb = t * HOP - PAD + nbase;
            #pragma unroll
            for (int r = 0; r < 4; ++r) {
                int o = sb + r;
                if ((unsigned)o < (unsigned)OUTB)
                    atomicAdd(&outb[o], acc[i][j][r] * wr4[r]);
            }
        }
    }
}

// ---------------- finalize: divide by env ----------------
__global__ void finalize_kernel(const float* __restrict__ window, float* __restrict__ out) {
    int o = blockIdx.x * 256 + threadIdx.x;
    if (o >= OUTB) return;
    int s = o + PAD;
    int tlo = (s - (WINL - 1) + (HOP - 1)) >> 8;
    if (tlo < 0) tlo = 0;
    int thi = s >> 8; if (thi > T_ - 1) thi = T_ - 1;
    float e = 0.f;
    for (int t = tlo; t <= thi; ++t) {
        float ww = window[s - (t << 8)];
        e += ww * ww;
    }
    float inv = 1.0f / (e + 1e-11f);
    #pragma unroll
    for (int b = 0; b < B_; ++b)
        out[(size_t)b * OUTB + o] *= inv;
}

// ---------------- launch ----------------
extern "C" void kernel_launch(void* const* d_in, const int* in_sizes, int n_in,
                              void* d_out, int out_size, void* d_ws, size_t ws_size,
                              hipStream_t stream) {
    const float* x      = (const float*)d_in[0];
    const float* W      = (const float*)d_in[1];
    const float* bias   = (const float*)d_in[2];
    const float* window = (const float*)d_in[3];
    float* out = (float*)d_out;

    const size_t basis_e = (size_t)NFFT * KB;        // ushort elems per basis buffer
    const size_t spec_e  = (size_t)T_ * KB;          // ushort elems per batch per buffer

    int bcount = B_;
    {
        size_t need = (2 * basis_e + 2 * (size_t)B_ * spec_e) * sizeof(ushort);
        if (ws_size < need) bcount = 1;
    }

    ushort* Ah = (ushort*)d_ws;
    ushort* Al = Ah + basis_e;
    ushort* Bh = Al + basis_e;
    ushort* Bl = Bh + (size_t)bcount * spec_e;

    hipMemsetAsync(d_out, 0, (size_t)out_size * sizeof(float), stream);
    basis_kernel<<<(NFFT * KB + 255) / 256, 256, 0, stream>>>(Ah, Al);

    for (int b0 = 0; b0 < B_; b0 += bcount) {
        dim3 ga(64 * bcount, 9);
        gemm_a_kernel<<<ga, 256, 0, stream>>>(x, W, bias, Bh, Bl, b0);
        dim3 gb(32, 8, bcount);
        gemm_b_mfma<<<gb, 256, 0, stream>>>(Ah, Al, Bh, Bl, window, out, b0);
    }
    finalize_kernel<<<(OUTB + 255) / 256, 256, 0, stream>>>(window, out);
}

// Round 3
// 750.265 us; speedup vs baseline: 1.8528x; 1.5397x over previous
//
#include <hip/hip_runtime.h>
#include <math.h>

#define B_  8
#define T_  4096
#define H_  512
#define FREQ 513
#define KP  528            // FREQ padded to 16
#define KB  1056           // 2*KP: [cos | -sin] concatenated along K
#define NFFT 1024
#define WINL 1024
#define HOP 256
#define PAD 384
#define OUTB 1048576       // per-batch output samples (cropped)
#define CLAMP_MAXV 100.0f

typedef __attribute__((ext_vector_type(8))) short bf16x8;
typedef __attribute__((ext_vector_type(4))) float f32x4;

__device__ inline ushort f2bf(float v) {
    union { float f; unsigned u; } x; x.f = v;
    unsigned r = x.u + 0x7FFFu + ((x.u >> 16) & 1u);   // RNE
    return (ushort)(r >> 16);
}
__device__ inline float bf2f(ushort h) {
    union { unsigned u; float f; } x; x.u = ((unsigned)h) << 16;
    return x.f;
}

#define GLOAD_LDS16(g, l) __builtin_amdgcn_global_load_lds( \
    (const __attribute__((address_space(1))) unsigned int*)(g), \
    (__attribute__((address_space(3))) unsigned int*)(l), 16, 0, 0)

// ---------------- basis precompute: A = [cos*scale | -sin*scale], split hi/lo bf16 ----------------
__global__ void basis_kernel(ushort* __restrict__ Ah, ushort* __restrict__ Al) {
    int idx = blockIdx.x * 256 + threadIdx.x;
    if (idx >= NFFT * KB) return;
    int n = idx / KB, k = idx - n * KB;
    float v = 0.f;
    int kk = (k < KP) ? k : (k - KP);
    if (kk < FREQ) {
        int m = (n * kk) & (NFFT - 1);
        float a = (float)m * 6.135923151542565e-3f;       // 2*pi/1024
        float sc = ((kk == 0) || (kk == FREQ - 1)) ? (1.0f / NFFT) : (2.0f / NFFT);
        v = (k < KP) ? (cosf(a) * sc) : (-sinf(a) * sc);
    }
    ushort h = f2bf(v);
    Ah[idx] = h;
    Al[idx] = f2bf(v - bf2f(h));
}

// ---------------- GEMM A: h = x@W + b (fp32), epilogue -> spec hi/lo bf16 at [t][k] ----------------
__global__ __launch_bounds__(256) void gemm_a_kernel(
    const float* __restrict__ x, const float* __restrict__ W,
    const float* __restrict__ bias,
    ushort* __restrict__ Bh, ushort* __restrict__ Bl, int b0)
{
    __shared__ float Xs[16][68];
    __shared__ float Wm[16][64];
    __shared__ float Wp[16][64];
    const int tid = threadIdx.x;
    const int tx = tid & 15;
    const int ty = tid >> 4;
    const int m0 = blockIdx.x * 64;
    const int f0 = blockIdx.y * 64;

    float accM[4][4] = {{0.f}};
    float accP[4][4] = {{0.f}};

    const int lr  = tid >> 2;
    const int lk  = (tid & 3) * 4;
    const int wc  = tid & 63;
    const int wk0 = (tid >> 6) * 4;

    const size_t grow = (size_t)(b0 * T_ + m0);

    for (int k0 = 0; k0 < H_; k0 += 16) {
        float4 xv = *reinterpret_cast<const float4*>(&x[(grow + lr) * H_ + k0 + lk]);
        Xs[lk + 0][lr] = xv.x; Xs[lk + 1][lr] = xv.y;
        Xs[lk + 2][lr] = xv.z; Xs[lk + 3][lr] = xv.w;

        int f = f0 + wc;
        #pragma unroll
        for (int q = 0; q < 4; ++q) {
            int k = wk0 + q;
            float vm = 0.f, vp = 0.f;
            if (f < FREQ) {
                vm = W[(size_t)(k0 + k) * (2 * FREQ) + f];
                vp = W[(size_t)(k0 + k) * (2 * FREQ) + FREQ + f];
            }
            Wm[k][wc] = vm; Wp[k][wc] = vp;
        }
        __syncthreads();
        #pragma unroll
        for (int kk = 0; kk < 16; ++kk) {
            float4 xa = *reinterpret_cast<const float4*>(&Xs[kk][tx * 4]);
            float4 wm = *reinterpret_cast<const float4*>(&Wm[kk][ty * 4]);
            float4 wp = *reinterpret_cast<const float4*>(&Wp[kk][ty * 4]);
            float xr[4]  = {xa.x, xa.y, xa.z, xa.w};
            float wmr[4] = {wm.x, wm.y, wm.z, wm.w};
            float wpr[4] = {wp.x, wp.y, wp.z, wp.w};
            #pragma unroll
            for (int i = 0; i < 4; ++i)
                #pragma unroll
                for (int j = 0; j < 4; ++j) {
                    accM[i][j] = fmaf(xr[i], wmr[j], accM[i][j]);
                    accP[i][j] = fmaf(xr[i], wpr[j], accP[i][j]);
                }
        }
        __syncthreads();
    }

    const int b_local = m0 >> 12;
    const int tbase = (m0 & (T_ - 1)) + tx * 4;
    const int fb = f0 + ty * 4;
    if (fb >= KP) return;
    ushort* Bh_b = Bh + (size_t)b_local * T_ * KB;
    ushort* Bl_b = Bl + (size_t)b_local * T_ * KB;

    #pragma unroll
    for (int i = 0; i < 4; ++i) {
        int t = tbase + i;
        ushort rh[4], rl[4], ih[4], il[4];
        #pragma unroll
        for (int j = 0; j < 4; ++j) {
            int f = fb + j;
            float re = 0.f, im = 0.f;
            if (f < FREQ) {
                float mag = fminf(expf(accM[i][j] + bias[f]), CLAMP_MAXV);
                float ph = accP[i][j] + bias[FREQ + f];
                float sp, cp;
                sincosf(ph, &sp, &cp);
                re = mag * cp; im = mag * sp;
            }
            ushort h1 = f2bf(re); rh[j] = h1; rl[j] = f2bf(re - bf2f(h1));
            ushort h2 = f2bf(im); ih[j] = h2; il[j] = f2bf(im - bf2f(h2));
        }
        size_t row = (size_t)t * KB;
        *reinterpret_cast<ushort4*>(&Bh_b[row + fb])      = make_ushort4(rh[0], rh[1], rh[2], rh[3]);
        *reinterpret_cast<ushort4*>(&Bl_b[row + fb])      = make_ushort4(rl[0], rl[1], rl[2], rl[3]);
        *reinterpret_cast<ushort4*>(&Bh_b[row + KP + fb]) = make_ushort4(ih[0], ih[1], ih[2], ih[3]);
        *reinterpret_cast<ushort4*>(&Bl_b[row + KP + fb]) = make_ushort4(il[0], il[1], il[2], il[3]);
    }
}

// ---------------- GEMM B (MFMA): frames[b][t][n] = (A@spec)*window, plain stores ----------------
// grid: (32 t-tiles, 8 n-tiles, bcount); block 256 (4 waves, 2x2).
__global__ __launch_bounds__(256) void gemm_b_mfma(
    const ushort* __restrict__ Ah, const ushort* __restrict__ Al,
    const ushort* __restrict__ Bh, const ushort* __restrict__ Bl,
    const float* __restrict__ window, float* __restrict__ frames, int b0)
{
    __shared__ __attribute__((aligned(16))) ushort sAh[128 * 32];
    __shared__ __attribute__((aligned(16))) ushort sAl[128 * 32];
    __shared__ __attribute__((aligned(16))) ushort sBh[128 * 32];
    __shared__ __attribute__((aligned(16))) ushort sBl[128 * 32];
    const int tid = threadIdx.x;
    const int lane = tid & 63;
    const int w = tid >> 6;
    const int wr = w >> 1, wc = w & 1;
    const int b_local = blockIdx.z;
    const int n0 = blockIdx.y * 128;
    const int t0 = blockIdx.x * 128;

    const ushort* Bh_b = Bh + (size_t)b_local * T_ * KB;
    const ushort* Bl_b = Bl + (size_t)b_local * T_ * KB;

    f32x4 acc[4][4] = {};

    const int srow = tid >> 2;           // staging row 0..63 (per q pass)
    const int selem = (tid & 3) * 8;     // staging k-elem offset
    const int arow = lane & 15;
    const int kch = (lane >> 4) * 8;

    const int ldsbase = w * 1024;        // wave-uniform
    char* pAh = (char*)sAh; char* pAl = (char*)sAl;
    char* pBh = (char*)sBh; char* pBl = (char*)sBl;

    for (int k0 = 0; k0 < KB; k0 += 32) {
        #pragma unroll
        for (int q = 0; q < 2; ++q) {
            size_t aoff = (size_t)(n0 + q * 64 + srow) * KB + k0 + selem;
            size_t boff = (size_t)(t0 + q * 64 + srow) * KB + k0 + selem;
            GLOAD_LDS16(Ah + aoff,   pAh + q * 4096 + ldsbase);
            GLOAD_LDS16(Al + aoff,   pAl + q * 4096 + ldsbase);
            GLOAD_LDS16(Bh_b + boff, pBh + q * 4096 + ldsbase);
            GLOAD_LDS16(Bl_b + boff, pBl + q * 4096 + ldsbase);
        }
        __syncthreads();
        bf16x8 ah[4], al[4], bh[4], bl[4];
        #pragma unroll
        for (int i = 0; i < 4; ++i) {
            int r = (wr * 64 + i * 16 + arow) * 32 + kch;
            ah[i] = *reinterpret_cast<const bf16x8*>(&sAh[r]);
            al[i] = *reinterpret_cast<const bf16x8*>(&sAl[r]);
        }
        #pragma unroll
        for (int j = 0; j < 4; ++j) {
            int r = (wc * 64 + j * 16 + arow) * 32 + kch;
            bh[j] = *reinterpret_cast<const bf16x8*>(&sBh[r]);
            bl[j] = *reinterpret_cast<const bf16x8*>(&sBl[r]);
        }
        #pragma unroll
        for (int i = 0; i < 4; ++i)
            #pragma unroll
            for (int j = 0; j < 4; ++j) {
                acc[i][j] = __builtin_amdgcn_mfma_f32_16x16x32_bf16(ah[i], bh[j], acc[i][j], 0, 0, 0);
                acc[i][j] = __builtin_amdgcn_mfma_f32_16x16x32_bf16(ah[i], bl[j], acc[i][j], 0, 0, 0);
                acc[i][j] = __builtin_amdgcn_mfma_f32_16x16x32_bf16(al[i], bh[j], acc[i][j], 0, 0, 0);
            }
        __syncthreads();
    }

    // epilogue: D row = n, col = t; frames[b][t][n] = D*window[n]
    const int crow = (lane >> 4) * 4;
    const int ccol = lane & 15;
    float* fb = frames + (size_t)b_local * T_ * NFFT;
    #pragma unroll
    for (int i = 0; i < 4; ++i) {
        int nbase = n0 + wr * 64 + i * 16 + crow;
        float4 wv = *reinterpret_cast<const float4*>(&window[nbase]);
        float wr4[4] = {wv.x, wv.y, wv.z, wv.w};
        #pragma unroll
        for (int j = 0; j < 4; ++j) {
            int t = t0 + wc * 64 + j * 16 + ccol;
            float4 st;
            st.x = acc[i][j][0] * wr4[0];
            st.y = acc[i][j][1] * wr4[1];
            st.z = acc[i][j][2] * wr4[2];
            st.w = acc[i][j][3] * wr4[3];
            *reinterpret_cast<float4*>(&fb[(size_t)t * NFFT + nbase]) = st;
        }
    }
}

// ---------------- OLA + env divide: out[b][o] = sum_q frames[b][t_q][n_q] / (env+eps) ----------------
__global__ void ola_kernel(const float* __restrict__ frames,
                           const float* __restrict__ window,
                           float* __restrict__ out, int b0, int bcount) {
    int o = blockIdx.x * 256 + threadIdx.x;
    if (o >= OUTB) return;
    int s = o + PAD;
    int thi = s >> 8;
    int tlo = thi - 3;
    if (thi > T_ - 1) thi = T_ - 1;
    if (tlo < 0) tlo = 0;
    float env = 0.f;
    for (int t = tlo; t <= thi; ++t) {
        float ww = window[s - (t << 8)];
        env += ww * ww;
    }
    float inv = 1.0f / (env + 1e-11f);
    for (int bl = 0; bl < bcount; ++bl) {
        const float* fb = frames + (size_t)bl * T_ * NFFT;
        float v = 0.f;
        for (int t = tlo; t <= thi; ++t)
            v += fb[(size_t)t * NFFT + (s - (t << 8))];
        out[(size_t)(b0 + bl) * OUTB + o] = v * inv;
    }
}

// ---------------- launch ----------------
extern "C" void kernel_launch(void* const* d_in, const int* in_sizes, int n_in,
                              void* d_out, int out_size, void* d_ws, size_t ws_size,
                              hipStream_t stream) {
    const float* x      = (const float*)d_in[0];
    const float* W      = (const float*)d_in[1];
    const float* bias   = (const float*)d_in[2];
    const float* window = (const float*)d_in[3];
    float* out = (float*)d_out;

    const size_t basis_e = (size_t)NFFT * KB;        // ushort elems per basis buffer
    const size_t spec_e  = (size_t)T_ * KB;          // ushort elems per batch per buffer
    const size_t frame_f = (size_t)T_ * NFFT;        // float elems per batch

    int bcount = 8;
    while (bcount > 1) {
        size_t need = 2 * basis_e * sizeof(ushort)
                    + (size_t)bcount * (2 * spec_e * sizeof(ushort) + frame_f * sizeof(float));
        if (need <= ws_size) break;
        bcount >>= 1;
    }

    ushort* Ah = (ushort*)d_ws;
    ushort* Al = Ah + basis_e;
    ushort* Bh = Al + basis_e;
    ushort* Bl = Bh + (size_t)bcount * spec_e;
    float* frames = (float*)(Bl + (size_t)bcount * spec_e);

    basis_kernel<<<(NFFT * KB + 255) / 256, 256, 0, stream>>>(Ah, Al);

    for (int b0 = 0; b0 < B_; b0 += bcount) {
        dim3 ga(64 * bcount, 9);
        gemm_a_kernel<<<ga, 256, 0, stream>>>(x, W, bias, Bh, Bl, b0);
        dim3 gb(32, 8, bcount);
        gemm_b_mfma<<<gb, 256, 0, stream>>>(Ah, Al, Bh, Bl, window, frames, b0);
        ola_kernel<<<(OUTB + 255) / 256, 256, 0, stream>>>(frames, window, out, b0, bcount);
    }
}

// Round 4
// 535.596 us; speedup vs baseline: 2.5954x; 1.4008x over previous
//
#include <hip/hip_runtime.h>
#include <math.h>

#define B_  8
#define T_  4096
#define H_  512
#define FREQ 513
#define KP  528            // FREQ padded to 16
#define KB  1056           // 2*KP: [cos | -sin] per spec row
#define K4  4224           // 4*KB: j-concatenated K for the OLA-GEMM
#define NW  576            // padded f for W (9 tiles of 64)
#define MTOT 4224          // m padded to 66 tiles of 64
#define SPEC_ROWS 4227     // 3 lead pad + 4096 + 128 trail pad
#define SPEC_E ((size_t)SPEC_ROWS * KB)
#define NFFT 1024
#define HOP 256
#define PAD 384
#define OUTB 1048576
#define CLAMP_MAXV 100.0f

typedef __attribute__((ext_vector_type(8))) short bf16x8;
typedef __attribute__((ext_vector_type(4))) float f32x4;

__device__ inline ushort f2bf(float v) {
    union { float f; unsigned u; } x; x.f = v;
    unsigned r = x.u + 0x7FFFu + ((x.u >> 16) & 1u);   // RNE
    return (ushort)(r >> 16);
}
__device__ inline float bf2f(ushort h) {
    union { unsigned u; float f; } x; x.u = ((unsigned)h) << 16;
    return x.f;
}

#define GLOAD_LDS16(g, l) __builtin_amdgcn_global_load_lds( \
    (const __attribute__((address_space(1))) unsigned int*)(g), \
    (__attribute__((address_space(3))) unsigned int*)(l), 16, 0, 0)

// ---------------- basis: A2[p][j*KB+k] = basisval(n=p+256j, k) * window[n], hi/lo bf16 ----------------
__global__ void basis_kernel(const float* __restrict__ window,
                             ushort* __restrict__ A2h, ushort* __restrict__ A2l) {
    int idx = blockIdx.x * 256 + threadIdx.x;   // [0, 1024*1056)
    int n = idx / KB, k = idx - n * KB;
    float v = 0.f;
    int kk = (k < KP) ? k : (k - KP);
    if (kk < FREQ) {
        int m = (n * kk) & (NFFT - 1);
        float a = (float)m * 6.135923151542565e-3f;       // 2*pi/1024
        float sc = ((kk == 0) || (kk == FREQ - 1)) ? (1.0f / NFFT) : (2.0f / NFFT);
        v = ((k < KP) ? cosf(a) : -sinf(a)) * sc * window[n];
    }
    int p = n & 255, j = n >> 8;
    size_t dst = (size_t)p * K4 + (size_t)j * KB + k;
    ushort h = f2bf(v);
    A2h[dst] = h;
    A2l[dst] = f2bf(v - bf2f(h));
}

// ---------------- W prep: Wm/Wp [f(576)][k(512)] hi/lo bf16 ----------------
__global__ void prepw_kernel(const float* __restrict__ W,
                             ushort* __restrict__ Wmh, ushort* __restrict__ Wml,
                             ushort* __restrict__ Wph, ushort* __restrict__ Wpl) {
    int idx = blockIdx.x * 256 + threadIdx.x;
    if (idx >= NW * H_) return;
    int k = idx / NW, f = idx - k * NW;
    float vm = 0.f, vp = 0.f;
    if (f < FREQ) {
        vm = W[(size_t)k * (2 * FREQ) + f];
        vp = W[(size_t)k * (2 * FREQ) + FREQ + f];
    }
    size_t dst = (size_t)f * H_ + k;
    ushort h1 = f2bf(vm); Wmh[dst] = h1; Wml[dst] = f2bf(vm - bf2f(h1));
    ushort h2 = f2bf(vp); Wph[dst] = h2; Wpl[dst] = f2bf(vp - bf2f(h2));
}

// ---------------- x conversion: fp32 -> hi/lo bf16 ----------------
__global__ void convx_kernel(const float* __restrict__ x,
                             ushort* __restrict__ xh, ushort* __restrict__ xl) {
    size_t i4 = ((size_t)blockIdx.x * 256 + threadIdx.x) * 4;
    float4 v = *reinterpret_cast<const float4*>(x + i4);
    ushort4 hh, ll;
    hh.x = f2bf(v.x); ll.x = f2bf(v.x - bf2f(hh.x));
    hh.y = f2bf(v.y); ll.y = f2bf(v.y - bf2f(hh.y));
    hh.z = f2bf(v.z); ll.z = f2bf(v.z - bf2f(hh.z));
    hh.w = f2bf(v.w); ll.w = f2bf(v.w - bf2f(hh.w));
    *reinterpret_cast<ushort4*>(xh + i4) = hh;
    *reinterpret_cast<ushort4*>(xl + i4) = ll;
}

// ---------------- spec pad rows zeroing ----------------
__global__ void padspec_kernel(ushort* __restrict__ Bh, ushort* __restrict__ Bl, int bcount) {
    const size_t stride = (size_t)131 * KB;
    size_t idx = (size_t)blockIdx.x * 256 + threadIdx.x;
    if (idx >= 2 * (size_t)bcount * stride) return;
    int q = (int)(idx / stride);
    size_t rem = idx - (size_t)q * stride;
    int r = (int)(rem / KB), c = (int)(rem - (size_t)r * KB);
    int row = (r < 3) ? r : (4096 + r);    // buffer rows 0..2 and 4099..4226
    ushort* p = ((q & 1) ? Bl : Bh) + (size_t)(q >> 1) * SPEC_E + (size_t)row * KB + c;
    *p = 0;
}

// ---------------- GEMM A (MFMA split-bf16): h = x@W + b, epilogue -> spec hi/lo ----------------
// grid: (bcount*32, 9); block 256 (4 waves 2x2). Tile 128 t x 64 f, K=512.
__global__ __launch_bounds__(256) void gemm_a_mfma(
    const ushort* __restrict__ xh, const ushort* __restrict__ xl,
    const ushort* __restrict__ Wmh, const ushort* __restrict__ Wml,
    const ushort* __restrict__ Wph, const ushort* __restrict__ Wpl,
    const float* __restrict__ bias,
    ushort* __restrict__ Bh, ushort* __restrict__ Bl, int b0)
{
    __shared__ __attribute__((aligned(16))) ushort sxh[128 * 32];
    __shared__ __attribute__((aligned(16))) ushort sxl[128 * 32];
    __shared__ __attribute__((aligned(16))) ushort smh[64 * 32];
    __shared__ __attribute__((aligned(16))) ushort sml[64 * 32];
    __shared__ __attribute__((aligned(16))) ushort sph[64 * 32];
    __shared__ __attribute__((aligned(16))) ushort spl[64 * 32];
    const int tid = threadIdx.x;
    const int lane = tid & 63;
    const int w = tid >> 6;
    const int wr = w >> 1, wc = w & 1;
    const int m0 = blockIdx.x * 128;     // row within launch (b0-relative)
    const int f0 = blockIdx.y * 64;

    const int srow = tid >> 2;
    const int ssel = ((tid & 3) ^ ((tid >> 3) & 3)) * 8;       // inverse-swizzled source chunk
    const int arow = lane & 15;
    const int kch  = (((lane >> 4) ^ ((arow >> 1) & 3))) * 8;  // swizzled read chunk

    f32x4 accM[4][2] = {};
    f32x4 accP[4][2] = {};

    const size_t xrow0 = (size_t)b0 * T_ + m0;
    char* pxh = (char*)sxh; char* pxl = (char*)sxl;
    char* pmh = (char*)smh; char* pml = (char*)sml;
    char* pph = (char*)sph; char* ppl = (char*)spl;

    for (int k0 = 0; k0 < H_; k0 += 32) {
        #pragma unroll
        for (int q = 0; q < 2; ++q) {
            size_t xo = (xrow0 + q * 64 + srow) * H_ + k0 + ssel;
            GLOAD_LDS16(xh + xo, pxh + q * 4096 + w * 1024);
            GLOAD_LDS16(xl + xo, pxl + q * 4096 + w * 1024);
        }
        size_t wo = (size_t)(f0 + srow) * H_ + k0 + ssel;
        GLOAD_LDS16(Wmh + wo, pmh + w * 1024);
        GLOAD_LDS16(Wml + wo, pml + w * 1024);
        GLOAD_LDS16(Wph + wo, pph + w * 1024);
        GLOAD_LDS16(Wpl + wo, ppl + w * 1024);
        __syncthreads();
        bf16x8 ah[4], al[4], bmh[2], bml[2], bph[2], bpl[2];
        #pragma unroll
        for (int i = 0; i < 4; ++i) {
            int r = (wr * 64 + i * 16 + arow) * 32 + kch;
            ah[i] = *reinterpret_cast<const bf16x8*>(&sxh[r]);
            al[i] = *reinterpret_cast<const bf16x8*>(&sxl[r]);
        }
        #pragma unroll
        for (int j = 0; j < 2; ++j) {
            int r = (wc * 32 + j * 16 + arow) * 32 + kch;
            bmh[j] = *reinterpret_cast<const bf16x8*>(&smh[r]);
            bml[j] = *reinterpret_cast<const bf16x8*>(&sml[r]);
            bph[j] = *reinterpret_cast<const bf16x8*>(&sph[r]);
            bpl[j] = *reinterpret_cast<const bf16x8*>(&spl[r]);
        }
        #pragma unroll
        for (int i = 0; i < 4; ++i)
            #pragma unroll
            for (int j = 0; j < 2; ++j) {
                accM[i][j] = __builtin_amdgcn_mfma_f32_16x16x32_bf16(ah[i], bmh[j], accM[i][j], 0, 0, 0);
                accM[i][j] = __builtin_amdgcn_mfma_f32_16x16x32_bf16(ah[i], bml[j], accM[i][j], 0, 0, 0);
                accM[i][j] = __builtin_amdgcn_mfma_f32_16x16x32_bf16(al[i], bmh[j], accM[i][j], 0, 0, 0);
                accP[i][j] = __builtin_amdgcn_mfma_f32_16x16x32_bf16(ah[i], bph[j], accP[i][j], 0, 0, 0);
                accP[i][j] = __builtin_amdgcn_mfma_f32_16x16x32_bf16(ah[i], bpl[j], accP[i][j], 0, 0, 0);
                accP[i][j] = __builtin_amdgcn_mfma_f32_16x16x32_bf16(al[i], bph[j], accP[i][j], 0, 0, 0);
            }
        __syncthreads();
    }

    // epilogue: C row = t, col = f; nonlinearity + hi/lo split -> spec [t][KB]
    const int ccol = lane & 15;
    const int rbase = (lane >> 4) * 4;
    const int b_local = m0 >> 12;
    ushort* BhB = Bh + (size_t)b_local * SPEC_E + 3 * KB;
    ushort* BlB = Bl + (size_t)b_local * SPEC_E + 3 * KB;
    const int t00 = (m0 & (T_ - 1)) + wr * 64 + rbase;

    #pragma unroll
    for (int j = 0; j < 2; ++j) {
        int f = f0 + wc * 32 + j * 16 + ccol;
        if (f >= KP) continue;
        bool live = (f < FREQ);
        float bm = live ? bias[f] : 0.f;
        float bp = live ? bias[FREQ + f] : 0.f;
        #pragma unroll
        for (int i = 0; i < 4; ++i) {
            #pragma unroll
            for (int r = 0; r < 4; ++r) {
                float re = 0.f, im = 0.f;
                if (live) {
                    float mag = fminf(expf(accM[i][j][r] + bm), CLAMP_MAXV);
                    float phv = accP[i][j][r] + bp;
                    float sp, cp; sincosf(phv, &sp, &cp);
                    re = mag * cp; im = mag * sp;
                }
                size_t off = (size_t)(t00 + i * 16 + r) * KB;
                ushort h1 = f2bf(re);
                BhB[off + f] = h1; BlB[off + f] = f2bf(re - bf2f(h1));
                ushort h2 = f2bf(im);
                BhB[off + KP + f] = h2; BlB[off + KP + f] = f2bf(im - bf2f(h2));
            }
        }
    }
}

// ---------------- GEMM B (MFMA): y[m][p] = A2[p] . B'[m], env-divide, direct store ----------------
// grid: (66 m-tiles, 2 p-tiles, bcount); block 256 (4 waves 2x2). Tile 128 p x 64 m, K=4224.
__global__ __launch_bounds__(256) void gemm_b_mfma(
    const ushort* __restrict__ A2h, const ushort* __restrict__ A2l,
    const ushort* __restrict__ Bh, const ushort* __restrict__ Bl,
    const float* __restrict__ window, float* __restrict__ out, int b0)
{
    __shared__ __attribute__((aligned(16))) ushort sAh[128 * 32];
    __shared__ __attribute__((aligned(16))) ushort sAl[128 * 32];
    __shared__ __attribute__((aligned(16))) ushort sBh[64 * 32];
    __shared__ __attribute__((aligned(16))) ushort sBl[64 * 32];
    __shared__ float inv4s[256];
    const int tid = threadIdx.x;
    const int lane = tid & 63;
    const int w = tid >> 6;
    const int wr = w >> 1, wc = w & 1;
    const int m0 = blockIdx.x * 64;
    const int p0 = blockIdx.y * 128;
    const int b_local = blockIdx.z;

    {   // interior env table: env4(p) = sum_j w^2(p+256j), p in [0,256)
        float e = 1e-11f;
        #pragma unroll
        for (int jj = 0; jj < 4; ++jj) {
            float wv = window[tid + 256 * jj];
            e += wv * wv;
        }
        inv4s[tid] = 1.0f / e;
    }

    const ushort* BhB = Bh + (size_t)b_local * SPEC_E;
    const ushort* BlB = Bl + (size_t)b_local * SPEC_E;

    const int srow = tid >> 2;
    const int ssel = ((tid & 3) ^ ((tid >> 3) & 3)) * 8;
    const int arow = lane & 15;
    const int kch  = (((lane >> 4) ^ ((arow >> 1) & 3))) * 8;

    f32x4 acc[4][2] = {};
    char* pAh = (char*)sAh; char* pAl = (char*)sAl;
    char* pBh = (char*)sBh; char* pBl = (char*)sBl;

    for (int js = 0; js < 4; ++js) {
        const ushort* bhj = BhB + (size_t)(m0 + 3 - js) * KB;
        const ushort* blj = BlB + (size_t)(m0 + 3 - js) * KB;
        const ushort* ahj = A2h + (size_t)js * KB;
        const ushort* alj = A2l + (size_t)js * KB;
        for (int kk0 = 0; kk0 < KB; kk0 += 32) {
            #pragma unroll
            for (int q = 0; q < 2; ++q) {
                size_t ao = (size_t)(p0 + q * 64 + srow) * K4 + kk0 + ssel;
                GLOAD_LDS16(ahj + ao, pAh + q * 4096 + w * 1024);
                GLOAD_LDS16(alj + ao, pAl + q * 4096 + w * 1024);
            }
            size_t bo = (size_t)srow * KB + kk0 + ssel;
            GLOAD_LDS16(bhj + bo, pBh + w * 1024);
            GLOAD_LDS16(blj + bo, pBl + w * 1024);
            __syncthreads();
            bf16x8 ah[4], al[4], bh[2], bl[2];
            #pragma unroll
            for (int i = 0; i < 4; ++i) {
                int r = (wr * 64 + i * 16 + arow) * 32 + kch;
                ah[i] = *reinterpret_cast<const bf16x8*>(&sAh[r]);
                al[i] = *reinterpret_cast<const bf16x8*>(&sAl[r]);
            }
            #pragma unroll
            for (int j = 0; j < 2; ++j) {
                int r = (wc * 32 + j * 16 + arow) * 32 + kch;
                bh[j] = *reinterpret_cast<const bf16x8*>(&sBh[r]);
                bl[j] = *reinterpret_cast<const bf16x8*>(&sBl[r]);
            }
            #pragma unroll
            for (int i = 0; i < 4; ++i)
                #pragma unroll
                for (int j = 0; j < 2; ++j) {
                    acc[i][j] = __builtin_amdgcn_mfma_f32_16x16x32_bf16(ah[i], bh[j], acc[i][j], 0, 0, 0);
                    acc[i][j] = __builtin_amdgcn_mfma_f32_16x16x32_bf16(ah[i], bl[j], acc[i][j], 0, 0, 0);
                    acc[i][j] = __builtin_amdgcn_mfma_f32_16x16x32_bf16(al[i], bh[j], acc[i][j], 0, 0, 0);
                }
            __syncthreads();
        }
    }

    // epilogue: C row = p, col = m; out[b][256m + p - 384] = acc * inv_env
    const int ccol = lane & 15;
    const int rbase = (lane >> 4) * 4;
    float* outb = out + (size_t)(b0 + b_local) * OUTB;
    #pragma unroll
    for (int i = 0; i < 4; ++i) {
        int pb = p0 + wr * 64 + i * 16 + rbase;
        #pragma unroll
        for (int j = 0; j < 2; ++j) {
            int m = m0 + wc * 32 + j * 16 + ccol;
            int o0 = m * HOP + pb - PAD;
            if ((unsigned)o0 >= (unsigned)OUTB) continue;   // group-of-4 uniform (pb % 4 == 0)
            bool interior = (m >= 3) && (m <= T_ - 1);
            float vv[4];
            #pragma unroll
            for (int r = 0; r < 4; ++r) {
                float e;
                if (interior) {
                    e = inv4s[pb + r];
                } else {
                    float env = 1e-11f;
                    #pragma unroll
                    for (int jj = 0; jj < 4; ++jj) {
                        int t = m - jj;
                        if (t >= 0 && t < T_) {
                            float wv = window[pb + r + 256 * jj];
                            env += wv * wv;
                        }
                    }
                    e = 1.0f / env;
                }
                vv[r] = acc[i][j][r] * e;
            }
            *reinterpret_cast<float4*>(&outb[o0]) = make_float4(vv[0], vv[1], vv[2], vv[3]);
        }
    }
}

// ---------------- launch ----------------
extern "C" void kernel_launch(void* const* d_in, const int* in_sizes, int n_in,
                              void* d_out, int out_size, void* d_ws, size_t ws_size,
                              hipStream_t stream) {
    const float* x      = (const float*)d_in[0];
    const float* W      = (const float*)d_in[1];
    const float* bias   = (const float*)d_in[2];
    const float* window = (const float*)d_in[3];
    float* out = (float*)d_out;

    const size_t A2e = (size_t)256 * K4;        // 1,081,344
    const size_t We  = (size_t)NW * H_;         //   294,912
    const size_t xe  = (size_t)B_ * T_ * H_;    // 16,777,216

    int bcount = B_;
    while (bcount > 1) {
        size_t need = (2 * A2e + 4 * We + 2 * xe + 2 * (size_t)bcount * SPEC_E) * sizeof(ushort);
        if (need <= ws_size) break;
        bcount >>= 1;
    }

    ushort* A2h = (ushort*)d_ws;
    ushort* A2l = A2h + A2e;
    ushort* Wmh = A2l + A2e;
    ushort* Wml = Wmh + We;
    ushort* Wph = Wml + We;
    ushort* Wpl = Wph + We;
    ushort* xhb = Wpl + We;
    ushort* xlb = xhb + xe;
    ushort* Bh  = xlb + xe;
    ushort* Bl  = Bh + (size_t)bcount * SPEC_E;

    basis_kernel<<<(NFFT * KB) / 256, 256, 0, stream>>>(window, A2h, A2l);
    prepw_kernel<<<(NW * H_ + 255) / 256, 256, 0, stream>>>(W, Wmh, Wml, Wph, Wpl);
    convx_kernel<<<(int)(xe / 4 / 256), 256, 0, stream>>>(x, xhb, xlb);
    {
        size_t padelems = 2 * (size_t)bcount * 131 * KB;
        padspec_kernel<<<(int)((padelems + 255) / 256), 256, 0, stream>>>(Bh, Bl, bcount);
    }

    for (int b0 = 0; b0 < B_; b0 += bcount) {
        dim3 ga(bcount * 32, 9);
        gemm_a_mfma<<<ga, 256, 0, stream>>>(xhb, xlb, Wmh, Wml, Wph, Wpl, bias, Bh, Bl, b0);
        dim3 gb(MTOT / 64, 2, bcount);
        gemm_b_mfma<<<gb, 256, 0, stream>>>(A2h, A2l, Bh, Bl, window, out, b0);
    }
}

// Round 6
// 427.697 us; speedup vs baseline: 3.2502x; 1.2523x over previous
//
#include <hip/hip_runtime.h>
#include <math.h>

#define B_  8
#define T_  4096
#define H_  512
#define FREQ 513
#define NW  576            // padded f for W (9 tiles of 64)
#define KE  544            // spec K: [re-part 272 | im-part 272], 17 x 32
#define KE2 272
#define NFFT 1024
#define HOP 256
#define PAD 384
#define OUTB 1048576
#define CLAMP_MAXV 100.0f
#define SE_E ((size_t)T_ * KE)     // spec elems per batch (per buffer)
#define EO_E ((size_t)T_ * NFFT)   // EO floats per batch

typedef __attribute__((ext_vector_type(8))) short bf16x8;
typedef __attribute__((ext_vector_type(4))) float f32x4;

__device__ inline ushort f2bf(float v) {
    union { float f; unsigned u; } x; x.f = v;
    unsigned r = x.u + 0x7FFFu + ((x.u >> 16) & 1u);   // RNE
    return (ushort)(r >> 16);
}
__device__ inline float bf2f(ushort h) {
    union { unsigned u; float f; } x; x.u = ((unsigned)h) << 16;
    return x.f;
}

#define GLOAD_LDS16(g, l) __builtin_amdgcn_global_load_lds( \
    (const __attribute__((address_space(1))) unsigned int*)(g), \
    (__attribute__((address_space(3))) unsigned int*)(l), 16, 0, 0)

// ---------------- basis: Ab[r][c], r<512: E half (k=2k'), r>=512: O half (k=2k'+1) ----------------
__global__ void basis_kernel(ushort* __restrict__ Abh, ushort* __restrict__ Abl) {
    int idx = blockIdx.x * 256 + threadIdx.x;   // [0, 1024*544)
    int r = idx / KE, c = idx - r * KE;
    int np = (r < 512) ? r : (r - 512);
    int kp = (c < KE2) ? c : (c - KE2);
    int k = (r < 512) ? (2 * kp) : (2 * kp + 1);
    float v = 0.f;
    bool valid = (r < 512) ? (kp <= 256) : (kp <= 255);
    if (valid) {
        int m = (np * k) & (NFFT - 1);
        float a = (float)m * 6.135923151542565e-3f;       // 2*pi/1024
        float sc = ((k == 0) || (k == 512)) ? (1.0f / NFFT) : (2.0f / NFFT);
        v = ((c < KE2) ? cosf(a) : -sinf(a)) * sc;
    }
    ushort h = f2bf(v);
    Abh[idx] = h;
    Abl[idx] = f2bf(v - bf2f(h));
}

// ---------------- W prep: Wm/Wp [f(576)][k(512)] hi/lo bf16 ----------------
__global__ void prepw_kernel(const float* __restrict__ W,
                             ushort* __restrict__ Wmh, ushort* __restrict__ Wml,
                             ushort* __restrict__ Wph, ushort* __restrict__ Wpl) {
    int idx = blockIdx.x * 256 + threadIdx.x;
    if (idx >= NW * H_) return;
    int k = idx / NW, f = idx - k * NW;
    float vm = 0.f, vp = 0.f;
    if (f < FREQ) {
        vm = W[(size_t)k * (2 * FREQ) + f];
        vp = W[(size_t)k * (2 * FREQ) + FREQ + f];
    }
    size_t dst = (size_t)f * H_ + k;
    ushort h1 = f2bf(vm); Wmh[dst] = h1; Wml[dst] = f2bf(vm - bf2f(h1));
    ushort h2 = f2bf(vp); Wph[dst] = h2; Wpl[dst] = f2bf(vp - bf2f(h2));
}

// ---------------- x conversion (per bcount-chunk): fp32 -> hi/lo bf16 ----------------
__global__ void convx_kernel(const float* __restrict__ x,
                             ushort* __restrict__ xh, ushort* __restrict__ xl, int b0) {
    size_t i4 = ((size_t)blockIdx.x * 256 + threadIdx.x) * 4;
    float4 v = *reinterpret_cast<const float4*>(x + (size_t)b0 * T_ * H_ + i4);
    ushort4 hh, ll;
    hh.x = f2bf(v.x); ll.x = f2bf(v.x - bf2f(hh.x));
    hh.y = f2bf(v.y); ll.y = f2bf(v.y - bf2f(hh.y));
    hh.z = f2bf(v.z); ll.z = f2bf(v.z - bf2f(hh.z));
    hh.w = f2bf(v.w); ll.w = f2bf(v.w - bf2f(hh.w));
    *reinterpret_cast<ushort4*>(xh + i4) = hh;
    *reinterpret_cast<ushort4*>(xl + i4) = ll;
}

// ---------------- GEMM A (MFMA split-bf16): h = x@W + b, epilogue -> specE/specO ----------------
// grid: (bcount*32, 9); block 256 (4 waves 2x2). Tile 128 t x 64 f, K=512.
__global__ __launch_bounds__(256) void gemm_a_mfma(
    const ushort* __restrict__ xh, const ushort* __restrict__ xl,
    const ushort* __restrict__ Wmh, const ushort* __restrict__ Wml,
    const ushort* __restrict__ Wph, const ushort* __restrict__ Wpl,
    const float* __restrict__ bias,
    ushort* __restrict__ SEh, ushort* __restrict__ SEl,
    ushort* __restrict__ SOh, ushort* __restrict__ SOl)
{
    __shared__ __attribute__((aligned(16))) ushort sxh[128 * 32];
    __shared__ __attribute__((aligned(16))) ushort sxl[128 * 32];
    __shared__ __attribute__((aligned(16))) ushort smh[64 * 32];
    __shared__ __attribute__((aligned(16))) ushort sml[64 * 32];
    __shared__ __attribute__((aligned(16))) ushort sph[64 * 32];
    __shared__ __attribute__((aligned(16))) ushort spl[64 * 32];
    const int tid = threadIdx.x;
    const int lane = tid & 63;
    const int w = tid >> 6;
    const int wr = w >> 1, wc = w & 1;
    const int m0 = blockIdx.x * 128;     // chunk-local row
    const int f0 = blockIdx.y * 64;

    const int srow = tid >> 2;
    const int ssel = ((tid & 3) ^ ((tid >> 3) & 3)) * 8;
    const int arow = lane & 15;
    const int kch  = (((lane >> 4) ^ ((arow >> 1) & 3))) * 8;

    f32x4 accM[4][2] = {};
    f32x4 accP[4][2] = {};

    const size_t xrow0 = (size_t)m0;     // chunk-local
    char* pxh = (char*)sxh; char* pxl = (char*)sxl;
    char* pmh = (char*)smh; char* pml = (char*)sml;
    char* pph = (char*)sph; char* ppl = (char*)spl;

    for (int k0 = 0; k0 < H_; k0 += 32) {
        #pragma unroll
        for (int q = 0; q < 2; ++q) {
            size_t xo = (xrow0 + q * 64 + srow) * H_ + k0 + ssel;
            GLOAD_LDS16(xh + xo, pxh + q * 4096 + w * 1024);
            GLOAD_LDS16(xl + xo, pxl + q * 4096 + w * 1024);
        }
        size_t wo = (size_t)(f0 + srow) * H_ + k0 + ssel;
        GLOAD_LDS16(Wmh + wo, pmh + w * 1024);
        GLOAD_LDS16(Wml + wo, pml + w * 1024);
        GLOAD_LDS16(Wph + wo, pph + w * 1024);
        GLOAD_LDS16(Wpl + wo, ppl + w * 1024);
        __syncthreads();
        bf16x8 ah[4], al[4], bmh[2], bml[2], bph[2], bpl[2];
        #pragma unroll
        for (int i = 0; i < 4; ++i) {
            int r = (wr * 64 + i * 16 + arow) * 32 + kch;
            ah[i] = *reinterpret_cast<const bf16x8*>(&sxh[r]);
            al[i] = *reinterpret_cast<const bf16x8*>(&sxl[r]);
        }
        #pragma unroll
        for (int j = 0; j < 2; ++j) {
            int r = (wc * 32 + j * 16 + arow) * 32 + kch;
            bmh[j] = *reinterpret_cast<const bf16x8*>(&smh[r]);
            bml[j] = *reinterpret_cast<const bf16x8*>(&sml[r]);
            bph[j] = *reinterpret_cast<const bf16x8*>(&sph[r]);
            bpl[j] = *reinterpret_cast<const bf16x8*>(&spl[r]);
        }
        #pragma unroll
        for (int i = 0; i < 4; ++i)
            #pragma unroll
            for (int j = 0; j < 2; ++j) {
                accM[i][j] = __builtin_amdgcn_mfma_f32_16x16x32_bf16(ah[i], bmh[j], accM[i][j], 0, 0, 0);
                accM[i][j] = __builtin_amdgcn_mfma_f32_16x16x32_bf16(ah[i], bml[j], accM[i][j], 0, 0, 0);
                accM[i][j] = __builtin_amdgcn_mfma_f32_16x16x32_bf16(al[i], bmh[j], accM[i][j], 0, 0, 0);
                accP[i][j] = __builtin_amdgcn_mfma_f32_16x16x32_bf16(ah[i], bph[j], accP[i][j], 0, 0, 0);
                accP[i][j] = __builtin_amdgcn_mfma_f32_16x16x32_bf16(ah[i], bpl[j], accP[i][j], 0, 0, 0);
                accP[i][j] = __builtin_amdgcn_mfma_f32_16x16x32_bf16(al[i], bph[j], accP[i][j], 0, 0, 0);
            }
        __syncthreads();
    }

    // epilogue: nonlinearity, parity-split write to specE/specO [t][544] hi/lo
    const int ccol = lane & 15;
    const int rbase = (lane >> 4) * 4;
    const int b_local = m0 >> 12;
    const size_t specoff = (size_t)b_local * SE_E;
    const int t00 = (m0 & (T_ - 1)) + wr * 64 + rbase;

    #pragma unroll
    for (int j = 0; j < 2; ++j) {
        int f = f0 + wc * 32 + j * 16 + ccol;
        if (f >= KE) continue;                 // f in [544,576): nothing to write
        bool live = (f < FREQ);
        float bm = live ? bias[f] : 0.f;
        float bp = live ? bias[FREQ + f] : 0.f;
        ushort* dh = (((f & 1) ? SOh : SEh) + specoff);
        ushort* dl = (((f & 1) ? SOl : SEl) + specoff);
        int kk = f >> 1;
        #pragma unroll
        for (int i = 0; i < 4; ++i) {
            #pragma unroll
            for (int r = 0; r < 4; ++r) {
                float re = 0.f, im = 0.f;
                if (live) {
                    float mag = fminf(expf(accM[i][j][r] + bm), CLAMP_MAXV);
                    float phv = accP[i][j][r] + bp;
                    float sp, cp; sincosf(phv, &sp, &cp);
                    re = mag * cp; im = mag * sp;
                }
                size_t off = (size_t)(t00 + i * 16 + r) * KE;
                ushort h1 = f2bf(re);
                dh[off + kk] = h1; dl[off + kk] = f2bf(re - bf2f(h1));
                ushort h2 = f2bf(im);
                dh[off + KE2 + kk] = h2; dl[off + KE2 + kk] = f2bf(im - bf2f(h2));
            }
        }
    }
}

// ---------------- stage 1 GEMM (MFMA): EO[b][t][n''] = basis . spec  ----------------
// grid: (8 n-tiles, 32 t-tiles, bcount); block 256 (4 waves 2x2). Tile 128 n x 128 t, K=544.
__global__ __launch_bounds__(256) void gemm_eo_mfma(
    const ushort* __restrict__ Abh, const ushort* __restrict__ Abl,
    const ushort* __restrict__ SEh, const ushort* __restrict__ SEl,
    const ushort* __restrict__ SOh, const ushort* __restrict__ SOl,
    float* __restrict__ EO)
{
    __shared__ __attribute__((aligned(16))) ushort sAh[128 * 32];
    __shared__ __attribute__((aligned(16))) ushort sAl[128 * 32];
    __shared__ __attribute__((aligned(16))) ushort sBh[128 * 32];
    __shared__ __attribute__((aligned(16))) ushort sBl[128 * 32];
    const int tid = threadIdx.x;
    const int lane = tid & 63;
    const int w = tid >> 6;
    const int wr = w >> 1, wc = w & 1;
    const int n0 = blockIdx.x * 128;
    const int t0 = blockIdx.y * 128;
    const int b_local = blockIdx.z;

    const ushort* Bsh = ((n0 < 512) ? SEh : SOh) + (size_t)b_local * SE_E;
    const ushort* Bsl = ((n0 < 512) ? SEl : SOl) + (size_t)b_local * SE_E;

    const int srow = tid >> 2;
    const int ssel = ((tid & 3) ^ ((tid >> 3) & 3)) * 8;
    const int arow = lane & 15;
    const int kch  = (((lane >> 4) ^ ((arow >> 1) & 3))) * 8;

    f32x4 acc[4][4] = {};
    char* pAh = (char*)sAh; char* pAl = (char*)sAl;
    char* pBh = (char*)sBh; char* pBl = (char*)sBl;

    for (int k0 = 0; k0 < KE; k0 += 32) {
        #pragma unroll
        for (int q = 0; q < 2; ++q) {
            size_t ao = (size_t)(n0 + q * 64 + srow) * KE + k0 + ssel;
            GLOAD_LDS16(Abh + ao, pAh + q * 4096 + w * 1024);
            GLOAD_LDS16(Abl + ao, pAl + q * 4096 + w * 1024);
            size_t bo = (size_t)(t0 + q * 64 + srow) * KE + k0 + ssel;
            GLOAD_LDS16(Bsh + bo, pBh + q * 4096 + w * 1024);
            GLOAD_LDS16(Bsl + bo, pBl + q * 4096 + w * 1024);
        }
        __syncthreads();
        bf16x8 ah[4], al[4], bh[4], bl[4];
        #pragma unroll
        for (int i = 0; i < 4; ++i) {
            int r = (wr * 64 + i * 16 + arow) * 32 + kch;
            ah[i] = *reinterpret_cast<const bf16x8*>(&sAh[r]);
            al[i] = *reinterpret_cast<const bf16x8*>(&sAl[r]);
        }
        #pragma unroll
        for (int j = 0; j < 4; ++j) {
            int r = (wc * 64 + j * 16 + arow) * 32 + kch;
            bh[j] = *reinterpret_cast<const bf16x8*>(&sBh[r]);
            bl[j] = *reinterpret_cast<const bf16x8*>(&sBl[r]);
        }
        #pragma unroll
        for (int i = 0; i < 4; ++i)
            #pragma unroll
            for (int j = 0; j < 4; ++j) {
                acc[i][j] = __builtin_amdgcn_mfma_f32_16x16x32_bf16(ah[i], bh[j], acc[i][j], 0, 0, 0);
                acc[i][j] = __builtin_amdgcn_mfma_f32_16x16x32_bf16(ah[i], bl[j], acc[i][j], 0, 0, 0);
                acc[i][j] = __builtin_amdgcn_mfma_f32_16x16x32_bf16(al[i], bh[j], acc[i][j], 0, 0, 0);
            }
        __syncthreads();
    }

    // epilogue: C row = n'', col = t; EO[b][t][n''] float4 stores
    const int ccol = lane & 15;
    const int rbase = (lane >> 4) * 4;
    float* eob = EO + (size_t)b_local * EO_E;
    #pragma unroll
    for (int i = 0; i < 4; ++i) {
        int nb = n0 + wr * 64 + i * 16 + rbase;
        #pragma unroll
        for (int j = 0; j < 4; ++j) {
            int t = t0 + wc * 64 + j * 16 + ccol;
            *reinterpret_cast<float4*>(&eob[(size_t)t * NFFT + nb]) =
                make_float4(acc[i][j][0], acc[i][j][1], acc[i][j][2], acc[i][j][3]);
        }
    }
}

// ---------------- gather: window * butterfly * OLA / env -> out ----------------
__global__ void gather_kernel(const float* __restrict__ EO,
                              const float* __restrict__ window,
                              float* __restrict__ out, int b0, int bcount) {
    int o = blockIdx.x * 256 + threadIdx.x;
    int s = o + PAD;
    int m = s >> 8, p = s & 255;
    float env = 1e-11f;
    float wv[4]; int tv[4]; int np[4]; float sg[4];
    #pragma unroll
    for (int j = 0; j < 4; ++j) {
        int t = m - j;
        bool ok = (t >= 0) && (t < T_);
        tv[j] = ok ? t : 0;
        np[j] = p + 256 * (j & 1);
        sg[j] = (j < 2) ? 1.f : -1.f;
        float ww = ok ? window[p + 256 * j] : 0.f;
        wv[j] = ww;
        env += ww * ww;
    }
    float inv = 1.0f / env;
    for (int bl = 0; bl < bcount; ++bl) {
        const float* eo = EO + (size_t)bl * EO_E;
        float y = 0.f;
        #pragma unroll
        for (int j = 0; j < 4; ++j) {
            const float* row = eo + (size_t)tv[j] * NFFT;
            float e = row[np[j]];
            float od = row[512 + np[j]];
            y = fmaf(wv[j], fmaf(sg[j], od, e), y);
        }
        out[(size_t)(b0 + bl) * OUTB + o] = y * inv;
    }
}

// ---------------- launch ----------------
extern "C" void kernel_launch(void* const* d_in, const int* in_sizes, int n_in,
                              void* d_out, int out_size, void* d_ws, size_t ws_size,
                              hipStream_t stream) {
    const float* x      = (const float*)d_in[0];
    const float* W      = (const float*)d_in[1];
    const float* bias   = (const float*)d_in[2];
    const float* window = (const float*)d_in[3];
    float* out = (float*)d_out;

    const size_t Ae  = (size_t)NFFT * KE;        //   557,056
    const size_t We  = (size_t)NW * H_;          //   294,912
    const size_t xeb = (size_t)T_ * H_;          // 2,097,152 per batch

    // choose the largest bcount whose footprint fits ws_size (checked down to 1)
    int bcount = B_;
    for (;;) {
        size_t need = (2 * Ae + 4 * We
                       + 2 * (size_t)bcount * xeb
                       + 4 * (size_t)bcount * SE_E) * sizeof(ushort)
                    + (size_t)bcount * EO_E * sizeof(float);
        if (need <= ws_size || bcount == 1) break;
        bcount >>= 1;
    }

    ushort* Abh = (ushort*)d_ws;
    ushort* Abl = Abh + Ae;
    ushort* Wmh = Abl + Ae;
    ushort* Wml = Wmh + We;
    ushort* Wph = Wml + We;
    ushort* Wpl = Wph + We;
    ushort* xhb = Wpl + We;
    ushort* xlb = xhb + (size_t)bcount * xeb;
    ushort* SEh = xlb + (size_t)bcount * xeb;
    ushort* SEl = SEh + (size_t)bcount * SE_E;
    ushort* SOh = SEl + (size_t)bcount * SE_E;
    ushort* SOl = SOh + (size_t)bcount * SE_E;
    float*  EO  = (float*)(SOl + (size_t)bcount * SE_E);

    basis_kernel<<<(NFFT * KE) / 256, 256, 0, stream>>>(Abh, Abl);
    prepw_kernel<<<(NW * H_ + 255) / 256, 256, 0, stream>>>(W, Wmh, Wml, Wph, Wpl);

    for (int b0 = 0; b0 < B_; b0 += bcount) {
        convx_kernel<<<(int)((size_t)bcount * xeb / 4 / 256), 256, 0, stream>>>(x, xhb, xlb, b0);
        dim3 ga(bcount * 32, 9);
        gemm_a_mfma<<<ga, 256, 0, stream>>>(xhb, xlb, Wmh, Wml, Wph, Wpl, bias,
                                            SEh, SEl, SOh, SOl);
        dim3 ge(8, 32, bcount);
        gemm_eo_mfma<<<ge, 256, 0, stream>>>(Abh, Abl, SEh, SEl, SOh, SOl, EO);
        gather_kernel<<<OUTB / 256, 256, 0, stream>>>(EO, window, out, b0, bcount);
    }
}

// Round 7
// 407.945 us; speedup vs baseline: 3.4076x; 1.0484x over previous
//
#include <hip/hip_runtime.h>
#include <math.h>

#define B_  8
#define T_  4096
#define H_  512
#define FREQ 513
#define NW  576            // padded f for W (9 tiles of 64)
#define KE  576            // spec K: interleaved [re,im] pairs, padded; 18 x 32; row = 1152B (128B-mult)
#define NFFT 1024
#define HOP 256
#define PAD 384
#define OUTB 1048576
#define CLAMP_MAXV 100.0f
#define SE_E ((size_t)T_ * KE)     // spec elems per batch (per buffer)
#define EO_E ((size_t)T_ * NFFT)   // EO floats per batch

typedef __attribute__((ext_vector_type(8))) short bf16x8;
typedef __attribute__((ext_vector_type(4))) float f32x4;

__device__ inline ushort f2bf(float v) {
    union { float f; unsigned u; } x; x.f = v;
    unsigned r = x.u + 0x7FFFu + ((x.u >> 16) & 1u);   // RNE
    return (ushort)(r >> 16);
}
__device__ inline float bf2f(ushort h) {
    union { unsigned u; float f; } x; x.u = ((unsigned)h) << 16;
    return x.f;
}

#define GLOAD_LDS16(g, l) __builtin_amdgcn_global_load_lds( \
    (const __attribute__((address_space(1))) unsigned int*)(g), \
    (__attribute__((address_space(3))) unsigned int*)(l), 16, 0, 0)

// ---------------- basis: Ab[r][c]; r<512: E half (k=2kk), r>=512: O half (k=2kk+1) ----------------
// kk = c>>1; c even: cos*scale, c odd: -sin*scale. Zeros in pad slots.
__global__ void basis_kernel(ushort* __restrict__ Abh, ushort* __restrict__ Abl) {
    int idx = blockIdx.x * 256 + threadIdx.x;   // [0, 1024*576)
    int r = idx / KE, c = idx - r * KE;
    int np = (r < 512) ? r : (r - 512);
    int kk = c >> 1;
    int k = (r < 512) ? (2 * kk) : (2 * kk + 1);
    float v = 0.f;
    bool valid = (r < 512) ? (kk <= 256) : (kk <= 255);
    if (valid) {
        int m = (np * k) & (NFFT - 1);
        float a = (float)m * 6.135923151542565e-3f;       // 2*pi/1024
        float sc = ((k == 0) || (k == 512)) ? (1.0f / NFFT) : (2.0f / NFFT);
        v = ((c & 1) ? -sinf(a) : cosf(a)) * sc;
    }
    ushort h = f2bf(v);
    Abh[idx] = h;
    Abl[idx] = f2bf(v - bf2f(h));
}

// ---------------- W prep: Wm/Wp [f(576)][k(512)] hi/lo bf16 ----------------
__global__ void prepw_kernel(const float* __restrict__ W,
                             ushort* __restrict__ Wmh, ushort* __restrict__ Wml,
                             ushort* __restrict__ Wph, ushort* __restrict__ Wpl) {
    int idx = blockIdx.x * 256 + threadIdx.x;
    if (idx >= NW * H_) return;
    int k = idx / NW, f = idx - k * NW;
    float vm = 0.f, vp = 0.f;
    if (f < FREQ) {
        vm = W[(size_t)k * (2 * FREQ) + f];
        vp = W[(size_t)k * (2 * FREQ) + FREQ + f];
    }
    size_t dst = (size_t)f * H_ + k;
    ushort h1 = f2bf(vm); Wmh[dst] = h1; Wml[dst] = f2bf(vm - bf2f(h1));
    ushort h2 = f2bf(vp); Wph[dst] = h2; Wpl[dst] = f2bf(vp - bf2f(h2));
}

// ---------------- x conversion (per bcount-chunk): fp32 -> hi/lo bf16 ----------------
__global__ void convx_kernel(const float* __restrict__ x,
                             ushort* __restrict__ xh, ushort* __restrict__ xl, int b0) {
    size_t i4 = ((size_t)blockIdx.x * 256 + threadIdx.x) * 4;
    float4 v = *reinterpret_cast<const float4*>(x + (size_t)b0 * T_ * H_ + i4);
    ushort4 hh, ll;
    hh.x = f2bf(v.x); ll.x = f2bf(v.x - bf2f(hh.x));
    hh.y = f2bf(v.y); ll.y = f2bf(v.y - bf2f(hh.y));
    hh.z = f2bf(v.z); ll.z = f2bf(v.z - bf2f(hh.z));
    hh.w = f2bf(v.w); ll.w = f2bf(v.w - bf2f(hh.w));
    *reinterpret_cast<ushort4*>(xh + i4) = hh;
    *reinterpret_cast<ushort4*>(xl + i4) = ll;
}

// ---------------- GEMM A (MFMA split-bf16): h = x@W + b, epilogue -> specE/specO (coalesced) --------
// grid: (bcount*32, 9); block 256 (4 waves 2x2). Tile 128 t x 64 f, K=512.
__global__ __launch_bounds__(256) void gemm_a_mfma(
    const ushort* __restrict__ xh, const ushort* __restrict__ xl,
    const ushort* __restrict__ Wmh, const ushort* __restrict__ Wml,
    const ushort* __restrict__ Wph, const ushort* __restrict__ Wpl,
    const float* __restrict__ bias,
    ushort* __restrict__ SEh, ushort* __restrict__ SEl,
    ushort* __restrict__ SOh, ushort* __restrict__ SOl)
{
    // 72KB: main staging uses first 16384 ushorts; epilogue reuses all 4*9216
    __shared__ __attribute__((aligned(16))) ushort SH[4 * 9216];
    ushort* sxh = SH;              // 128x32
    ushort* sxl = SH + 4096;       // 128x32
    ushort* smh = SH + 8192;       // 64x32
    ushort* sml = SH + 10240;
    ushort* sph = SH + 12288;
    ushort* spl = SH + 14336;

    const int tid = threadIdx.x;
    const int lane = tid & 63;
    const int w = tid >> 6;
    const int wr = w >> 1, wc = w & 1;
    const int m0 = blockIdx.x * 128;     // chunk-local row
    const int f0 = blockIdx.y * 64;

    const int srow = tid >> 2;
    const int ssel = ((tid & 3) ^ ((tid >> 3) & 3)) * 8;
    const int arow = lane & 15;
    const int kch  = (((lane >> 4) ^ ((arow >> 1) & 3))) * 8;

    f32x4 accM[4][2] = {};
    f32x4 accP[4][2] = {};

    const size_t xrow0 = (size_t)m0;     // chunk-local
    char* pSH = (char*)SH;

    for (int k0 = 0; k0 < H_; k0 += 32) {
        #pragma unroll
        for (int q = 0; q < 2; ++q) {
            size_t xo = (xrow0 + q * 64 + srow) * H_ + k0 + ssel;
            GLOAD_LDS16(xh + xo, pSH + 0     + q * 4096 + w * 1024);
            GLOAD_LDS16(xl + xo, pSH + 8192  + q * 4096 + w * 1024);
        }
        size_t wo = (size_t)(f0 + srow) * H_ + k0 + ssel;
        GLOAD_LDS16(Wmh + wo, pSH + 16384 + w * 1024);
        GLOAD_LDS16(Wml + wo, pSH + 20480 + w * 1024);
        GLOAD_LDS16(Wph + wo, pSH + 24576 + w * 1024);
        GLOAD_LDS16(Wpl + wo, pSH + 28672 + w * 1024);
        __syncthreads();
        bf16x8 ah[4], al[4], bmh[2], bml[2], bph[2], bpl[2];
        #pragma unroll
        for (int i = 0; i < 4; ++i) {
            int r = (wr * 64 + i * 16 + arow) * 32 + kch;
            ah[i] = *reinterpret_cast<const bf16x8*>(&sxh[r]);
            al[i] = *reinterpret_cast<const bf16x8*>(&sxl[r]);
        }
        #pragma unroll
        for (int j = 0; j < 2; ++j) {
            int r = (wc * 32 + j * 16 + arow) * 32 + kch;
            bmh[j] = *reinterpret_cast<const bf16x8*>(&smh[r]);
            bml[j] = *reinterpret_cast<const bf16x8*>(&sml[r]);
            bph[j] = *reinterpret_cast<const bf16x8*>(&sph[r]);
            bpl[j] = *reinterpret_cast<const bf16x8*>(&spl[r]);
        }
        #pragma unroll
        for (int i = 0; i < 4; ++i)
            #pragma unroll
            for (int j = 0; j < 2; ++j) {
                accM[i][j] = __builtin_amdgcn_mfma_f32_16x16x32_bf16(ah[i], bmh[j], accM[i][j], 0, 0, 0);
                accM[i][j] = __builtin_amdgcn_mfma_f32_16x16x32_bf16(ah[i], bml[j], accM[i][j], 0, 0, 0);
                accM[i][j] = __builtin_amdgcn_mfma_f32_16x16x32_bf16(al[i], bmh[j], accM[i][j], 0, 0, 0);
                accP[i][j] = __builtin_amdgcn_mfma_f32_16x16x32_bf16(ah[i], bph[j], accP[i][j], 0, 0, 0);
                accP[i][j] = __builtin_amdgcn_mfma_f32_16x16x32_bf16(ah[i], bpl[j], accP[i][j], 0, 0, 0);
                accP[i][j] = __builtin_amdgcn_mfma_f32_16x16x32_bf16(al[i], bph[j], accP[i][j], 0, 0, 0);
            }
        __syncthreads();
    }

    // ---- epilogue: nonlinearity -> LDS transpose tiles -> coalesced 128B-row writes ----
    // Tiles (72-ushort padded rows): tau 0:SEh 1:SOh 2:SEl 3:SOl, each [128 t][64 kappa]
    const int ccol = lane & 15;
    const int rbase = (lane >> 4) * 4;
    const int b_local = m0 >> 12;
    const int t00blk = m0 & (T_ - 1);
    const size_t specoff = (size_t)b_local * SE_E;

    #pragma unroll
    for (int j = 0; j < 2; ++j) {
        int u = wc * 32 + j * 16 + ccol;     // 0..63 within f-tile
        int f = f0 + u;
        int par = u & 1;                     // 0 -> SE, 1 -> SO
        int kl = u & ~1;                     // kappa within tile (even)
        bool live = (f < FREQ);
        float bm = live ? bias[f] : 0.f;
        float bp = live ? bias[FREQ + f] : 0.f;
        #pragma unroll
        for (int i = 0; i < 4; ++i) {
            #pragma unroll
            for (int r = 0; r < 4; ++r) {
                float re = 0.f, im = 0.f;
                if (live) {
                    float mag = fminf(__expf(accM[i][j][r] + bm), CLAMP_MAXV);
                    float phv = accP[i][j][r] + bp;
                    float sp, cp; sincosf(phv, &sp, &cp);
                    re = mag * cp; im = mag * sp;
                }
                int tl = wr * 64 + i * 16 + rbase + r;
                ushort rh = f2bf(re), ih = f2bf(im);
                ushort rl = f2bf(re - bf2f(rh)), il = f2bf(im - bf2f(ih));
                int base = tl * 72 + kl;
                *reinterpret_cast<ushort2*>(&SH[par * 9216 + base])       = make_ushort2(rh, ih);
                *reinterpret_cast<ushort2*>(&SH[(2 + par) * 9216 + base]) = make_ushort2(rl, il);
            }
        }
    }
    __syncthreads();

    ushort* const bufs[4] = { SEh + specoff, SOh + specoff, SEl + specoff, SOl + specoff };
    const int row0 = tid >> 3;     // 0..31
    const int c8 = (tid & 7) * 8;  // ushort chunk within 64
    #pragma unroll
    for (int tau = 0; tau < 4; ++tau) {
        ushort* bp_ = bufs[tau];
        #pragma unroll
        for (int q2 = 0; q2 < 4; ++q2) {
            int row = q2 * 32 + row0;
            bf16x8 v = *reinterpret_cast<const bf16x8*>(&SH[tau * 9216 + row * 72 + c8]);
            *reinterpret_cast<bf16x8*>(&bp_[(size_t)(t00blk + row) * KE + f0 + c8]) = v;
        }
    }
}

// ---------------- stage 1 GEMM (MFMA): EO[b][t][n''] = basis . spec  ----------------
// grid: (8 n-tiles, 32 t-tiles, bcount); block 256 (4 waves 2x2). Tile 128 n x 128 t, K=576.
__global__ __launch_bounds__(256) void gemm_eo_mfma(
    const ushort* __restrict__ Abh, const ushort* __restrict__ Abl,
    const ushort* __restrict__ SEh, const ushort* __restrict__ SEl,
    const ushort* __restrict__ SOh, const ushort* __restrict__ SOl,
    float* __restrict__ EO)
{
    __shared__ __attribute__((aligned(16))) ushort sAh[128 * 32];
    __shared__ __attribute__((aligned(16))) ushort sAl[128 * 32];
    __shared__ __attribute__((aligned(16))) ushort sBh[128 * 32];
    __shared__ __attribute__((aligned(16))) ushort sBl[128 * 32];
    const int tid = threadIdx.x;
    const int lane = tid & 63;
    const int w = tid >> 6;
    const int wr = w >> 1, wc = w & 1;
    const int n0 = blockIdx.x * 128;
    const int t0 = blockIdx.y * 128;
    const int b_local = blockIdx.z;

    const ushort* Bsh = ((n0 < 512) ? SEh : SOh) + (size_t)b_local * SE_E;
    const ushort* Bsl = ((n0 < 512) ? SEl : SOl) + (size_t)b_local * SE_E;

    const int srow = tid >> 2;
    const int ssel = ((tid & 3) ^ ((tid >> 3) & 3)) * 8;
    const int arow = lane & 15;
    const int kch  = (((lane >> 4) ^ ((arow >> 1) & 3))) * 8;

    f32x4 acc[4][4] = {};
    char* pAh = (char*)sAh; char* pAl = (char*)sAl;
    char* pBh = (char*)sBh; char* pBl = (char*)sBl;

    for (int k0 = 0; k0 < KE; k0 += 32) {
        #pragma unroll
        for (int q = 0; q < 2; ++q) {
            size_t ao = (size_t)(n0 + q * 64 + srow) * KE + k0 + ssel;
            GLOAD_LDS16(Abh + ao, pAh + q * 4096 + w * 1024);
            GLOAD_LDS16(Abl + ao, pAl + q * 4096 + w * 1024);
            size_t bo = (size_t)(t0 + q * 64 + srow) * KE + k0 + ssel;
            GLOAD_LDS16(Bsh + bo, pBh + q * 4096 + w * 1024);
            GLOAD_LDS16(Bsl + bo, pBl + q * 4096 + w * 1024);
        }
        __syncthreads();
        bf16x8 ah[4], al[4], bh[4], bl[4];
        #pragma unroll
        for (int i = 0; i < 4; ++i) {
            int r = (wr * 64 + i * 16 + arow) * 32 + kch;
            ah[i] = *reinterpret_cast<const bf16x8*>(&sAh[r]);
            al[i] = *reinterpret_cast<const bf16x8*>(&sAl[r]);
        }
        #pragma unroll
        for (int j = 0; j < 4; ++j) {
            int r = (wc * 64 + j * 16 + arow) * 32 + kch;
            bh[j] = *reinterpret_cast<const bf16x8*>(&sBh[r]);
            bl[j] = *reinterpret_cast<const bf16x8*>(&sBl[r]);
        }
        #pragma unroll
        for (int i = 0; i < 4; ++i)
            #pragma unroll
            for (int j = 0; j < 4; ++j) {
                acc[i][j] = __builtin_amdgcn_mfma_f32_16x16x32_bf16(ah[i], bh[j], acc[i][j], 0, 0, 0);
                acc[i][j] = __builtin_amdgcn_mfma_f32_16x16x32_bf16(ah[i], bl[j], acc[i][j], 0, 0, 0);
                acc[i][j] = __builtin_amdgcn_mfma_f32_16x16x32_bf16(al[i], bh[j], acc[i][j], 0, 0, 0);
            }
        __syncthreads();
    }

    // epilogue: C row = n'', col = t; EO[b][t][n''] float4 stores
    const int ccol = lane & 15;
    const int rbase = (lane >> 4) * 4;
    float* eob = EO + (size_t)b_local * EO_E;
    #pragma unroll
    for (int i = 0; i < 4; ++i) {
        int nb = n0 + wr * 64 + i * 16 + rbase;
        #pragma unroll
        for (int j = 0; j < 4; ++j) {
            int t = t0 + wc * 64 + j * 16 + ccol;
            *reinterpret_cast<float4*>(&eob[(size_t)t * NFFT + nb]) =
                make_float4(acc[i][j][0], acc[i][j][1], acc[i][j][2], acc[i][j][3]);
        }
    }
}

// ---------------- gather: window * butterfly * OLA / env -> out ----------------
__global__ void gather_kernel(const float* __restrict__ EO,
                              const float* __restrict__ window,
                              float* __restrict__ out, int b0, int bcount) {
    int o = blockIdx.x * 256 + threadIdx.x;
    int s = o + PAD;
    int m = s >> 8, p = s & 255;
    float env = 1e-11f;
    float wv[4]; int tv[4]; int np[4]; float sg[4];
    #pragma unroll
    for (int j = 0; j < 4; ++j) {
        int t = m - j;
        bool ok = (t >= 0) && (t < T_);
        tv[j] = ok ? t : 0;
        np[j] = p + 256 * (j & 1);
        sg[j] = (j < 2) ? 1.f : -1.f;
        float ww = ok ? window[p + 256 * j] : 0.f;
        wv[j] = ww;
        env += ww * ww;
    }
    float inv = 1.0f / env;
    for (int bl = 0; bl < bcount; ++bl) {
        const float* eo = EO + (size_t)bl * EO_E;
        float y = 0.f;
        #pragma unroll
        for (int j = 0; j < 4; ++j) {
            const float* row = eo + (size_t)tv[j] * NFFT;
            float e = row[np[j]];
            float od = row[512 + np[j]];
            y = fmaf(wv[j], fmaf(sg[j], od, e), y);
        }
        out[(size_t)(b0 + bl) * OUTB + o] = y * inv;
    }
}

// ---------------- launch ----------------
extern "C" void kernel_launch(void* const* d_in, const int* in_sizes, int n_in,
                              void* d_out, int out_size, void* d_ws, size_t ws_size,
                              hipStream_t stream) {
    const float* x      = (const float*)d_in[0];
    const float* W      = (const float*)d_in[1];
    const float* bias   = (const float*)d_in[2];
    const float* window = (const float*)d_in[3];
    float* out = (float*)d_out;

    const size_t Ae  = (size_t)NFFT * KE;        //   589,824
    const size_t We  = (size_t)NW * H_;          //   294,912
    const size_t xeb = (size_t)T_ * H_;          // 2,097,152 per batch

    // bcount: largest that fits. Layout: [A|W|spec(4 bufs)|x(h,l)] with EO aliased
    // over the x region (x dead before gemm_eo writes EO; stream order makes it safe).
    // tail = bcount*EO_E*4B always >= x bytes (2*xeb*2B per batch).
    int bcount = B_;
    for (;;) {
        size_t prefix = (2 * Ae + 4 * We + 4 * (size_t)bcount * SE_E) * sizeof(ushort);
        size_t tail = (size_t)bcount * EO_E * sizeof(float);
        if (prefix + tail <= ws_size || bcount == 1) break;
        bcount >>= 1;
    }

    ushort* Abh = (ushort*)d_ws;
    ushort* Abl = Abh + Ae;
    ushort* Wmh = Abl + Ae;
    ushort* Wml = Wmh + We;
    ushort* Wph = Wml + We;
    ushort* Wpl = Wph + We;
    ushort* SEh = Wpl + We;
    ushort* SEl = SEh + (size_t)bcount * SE_E;
    ushort* SOh = SEl + (size_t)bcount * SE_E;
    ushort* SOl = SOh + (size_t)bcount * SE_E;
    ushort* xhb = SOl + (size_t)bcount * SE_E;
    ushort* xlb = xhb + (size_t)bcount * xeb;
    float*  EO  = (float*)xhb;                    // aliases x region (+extends past it)

    basis_kernel<<<(NFFT * KE) / 256, 256, 0, stream>>>(Abh, Abl);
    prepw_kernel<<<(NW * H_ + 255) / 256, 256, 0, stream>>>(W, Wmh, Wml, Wph, Wpl);

    for (int b0 = 0; b0 < B_; b0 += bcount) {
        convx_kernel<<<(int)((size_t)bcount * xeb / 4 / 256), 256, 0, stream>>>(x, xhb, xlb, b0);
        dim3 ga(bcount * 32, 9);
        gemm_a_mfma<<<ga, 256, 0, stream>>>(xhb, xlb, Wmh, Wml, Wph, Wpl, bias,
                                            SEh, SEl, SOh, SOl);
        dim3 ge(8, 32, bcount);
        gemm_eo_mfma<<<ge, 256, 0, stream>>>(Abh, Abl, SEh, SEl, SOh, SOl, EO);
        gather_kernel<<<OUTB / 256, 256, 0, stream>>>(EO, window, out, b0, bcount);
    }
}

// Round 8
// 396.101 us; speedup vs baseline: 3.5095x; 1.0299x over previous
//
#include <hip/hip_runtime.h>
#include <math.h>

#define B_  8
#define T_  4096
#define H_  512
#define FREQ 513
#define NW  576            // padded f for W (9 tiles of 64)
#define KE  576            // spec K: interleaved [re,im] pairs, padded; 18 x 32; row = 1152B
#define NFFT 1024
#define HOP 256
#define PAD 384
#define OUTB 1048576
#define CLAMP_MAXV 100.0f
#define SE_E ((size_t)T_ * KE)     // spec elems per batch (per buffer)
#define EO_E ((size_t)T_ * NFFT)   // EO floats per batch

typedef __attribute__((ext_vector_type(8))) short bf16x8;
typedef __attribute__((ext_vector_type(4))) float f32x4;

__device__ inline ushort f2bf(float v) {
    union { float f; unsigned u; } x; x.f = v;
    unsigned r = x.u + 0x7FFFu + ((x.u >> 16) & 1u);   // RNE
    return (ushort)(r >> 16);
}
__device__ inline float bf2f(ushort h) {
    union { unsigned u; float f; } x; x.u = ((unsigned)h) << 16;
    return x.f;
}

#define GLOAD_LDS16(g, l) __builtin_amdgcn_global_load_lds( \
    (const __attribute__((address_space(1))) unsigned int*)(g), \
    (__attribute__((address_space(3))) unsigned int*)(l), 16, 0, 0)

// ---------------- basis: Ab[r][c]; r<512: E half (k=2kk), r>=512: O half (k=2kk+1) ----------------
__global__ void basis_kernel(ushort* __restrict__ Abh, ushort* __restrict__ Abl) {
    int idx = blockIdx.x * 256 + threadIdx.x;   // [0, 1024*576)
    int r = idx / KE, c = idx - r * KE;
    int np = (r < 512) ? r : (r - 512);
    int kk = c >> 1;
    int k = (r < 512) ? (2 * kk) : (2 * kk + 1);
    float v = 0.f;
    bool valid = (r < 512) ? (kk <= 256) : (kk <= 255);
    if (valid) {
        int m = (np * k) & (NFFT - 1);
        float a = (float)m * 6.135923151542565e-3f;       // 2*pi/1024
        float sc = ((k == 0) || (k == 512)) ? (1.0f / NFFT) : (2.0f / NFFT);
        v = ((c & 1) ? -sinf(a) : cosf(a)) * sc;
    }
    ushort h = f2bf(v);
    Abh[idx] = h;
    Abl[idx] = f2bf(v - bf2f(h));
}

// ---------------- W prep: Wm/Wp [f(576)][k(512)] hi/lo bf16 ----------------
__global__ void prepw_kernel(const float* __restrict__ W,
                             ushort* __restrict__ Wmh, ushort* __restrict__ Wml,
                             ushort* __restrict__ Wph, ushort* __restrict__ Wpl) {
    int idx = blockIdx.x * 256 + threadIdx.x;
    if (idx >= NW * H_) return;
    int k = idx / NW, f = idx - k * NW;
    float vm = 0.f, vp = 0.f;
    if (f < FREQ) {
        vm = W[(size_t)k * (2 * FREQ) + f];
        vp = W[(size_t)k * (2 * FREQ) + FREQ + f];
    }
    size_t dst = (size_t)f * H_ + k;
    ushort h1 = f2bf(vm); Wmh[dst] = h1; Wml[dst] = f2bf(vm - bf2f(h1));
    ushort h2 = f2bf(vp); Wph[dst] = h2; Wpl[dst] = f2bf(vp - bf2f(h2));
}

// ---------------- x conversion (per bcount-chunk): fp32 -> hi/lo bf16 ----------------
__global__ void convx_kernel(const float* __restrict__ x,
                             ushort* __restrict__ xh, ushort* __restrict__ xl, int b0) {
    size_t i4 = ((size_t)blockIdx.x * 256 + threadIdx.x) * 4;
    float4 v = *reinterpret_cast<const float4*>(x + (size_t)b0 * T_ * H_ + i4);
    ushort4 hh, ll;
    hh.x = f2bf(v.x); ll.x = f2bf(v.x - bf2f(hh.x));
    hh.y = f2bf(v.y); ll.y = f2bf(v.y - bf2f(hh.y));
    hh.z = f2bf(v.z); ll.z = f2bf(v.z - bf2f(hh.z));
    hh.w = f2bf(v.w); ll.w = f2bf(v.w - bf2f(hh.w));
    *reinterpret_cast<ushort4*>(xh + i4) = hh;
    *reinterpret_cast<ushort4*>(xl + i4) = ll;
}

// ---------------- GEMM A (MFMA split-bf16): h = x@W + b, epilogue -> specE/specO (2-pass) --------
// grid: (bcount*32, 9); block 256 (4 waves 2x2). Tile 128 t x 64 f, K=512.
// LDS = 36864B -> 4 blocks/CU.
__global__ __launch_bounds__(256) void gemm_a_mfma(
    const ushort* __restrict__ xh, const ushort* __restrict__ xl,
    const ushort* __restrict__ Wmh, const ushort* __restrict__ Wml,
    const ushort* __restrict__ Wph, const ushort* __restrict__ Wpl,
    const float* __restrict__ bias,
    ushort* __restrict__ SEh, ushort* __restrict__ SEl,
    ushort* __restrict__ SOh, ushort* __restrict__ SOl)
{
    // main staging: first 16384 ushorts; epilogue: 2 tiles x 128x72 = 18432 ushorts
    __shared__ __attribute__((aligned(16))) ushort SH[18432];
    ushort* sxh = SH;              // 128x32
    ushort* sxl = SH + 4096;       // 128x32
    ushort* smh = SH + 8192;       // 64x32
    ushort* sml = SH + 10240;
    ushort* sph = SH + 12288;
    ushort* spl = SH + 14336;

    const int tid = threadIdx.x;
    const int lane = tid & 63;
    const int w = tid >> 6;
    const int wr = w >> 1, wc = w & 1;
    const int m0 = blockIdx.x * 128;     // chunk-local row
    const int f0 = blockIdx.y * 64;

    const int srow = tid >> 2;
    const int ssel = ((tid & 3) ^ ((tid >> 3) & 3)) * 8;
    const int arow = lane & 15;
    const int kch  = (((lane >> 4) ^ ((arow >> 1) & 3))) * 8;

    f32x4 accM[4][2] = {};
    f32x4 accP[4][2] = {};

    const size_t xrow0 = (size_t)m0;     // chunk-local
    char* pSH = (char*)SH;

    for (int k0 = 0; k0 < H_; k0 += 32) {
        #pragma unroll
        for (int q = 0; q < 2; ++q) {
            size_t xo = (xrow0 + q * 64 + srow) * H_ + k0 + ssel;
            GLOAD_LDS16(xh + xo, pSH + 0     + q * 4096 + w * 1024);
            GLOAD_LDS16(xl + xo, pSH + 8192  + q * 4096 + w * 1024);
        }
        size_t wo = (size_t)(f0 + srow) * H_ + k0 + ssel;
        GLOAD_LDS16(Wmh + wo, pSH + 16384 + w * 1024);
        GLOAD_LDS16(Wml + wo, pSH + 20480 + w * 1024);
        GLOAD_LDS16(Wph + wo, pSH + 24576 + w * 1024);
        GLOAD_LDS16(Wpl + wo, pSH + 28672 + w * 1024);
        __syncthreads();
        bf16x8 ah[4], al[4], bmh[2], bml[2], bph[2], bpl[2];
        #pragma unroll
        for (int i = 0; i < 4; ++i) {
            int r = (wr * 64 + i * 16 + arow) * 32 + kch;
            ah[i] = *reinterpret_cast<const bf16x8*>(&sxh[r]);
            al[i] = *reinterpret_cast<const bf16x8*>(&sxl[r]);
        }
        #pragma unroll
        for (int j = 0; j < 2; ++j) {
            int r = (wc * 32 + j * 16 + arow) * 32 + kch;
            bmh[j] = *reinterpret_cast<const bf16x8*>(&smh[r]);
            bml[j] = *reinterpret_cast<const bf16x8*>(&sml[r]);
            bph[j] = *reinterpret_cast<const bf16x8*>(&sph[r]);
            bpl[j] = *reinterpret_cast<const bf16x8*>(&spl[r]);
        }
        #pragma unroll
        for (int i = 0; i < 4; ++i)
            #pragma unroll
            for (int j = 0; j < 2; ++j) {
                accM[i][j] = __builtin_amdgcn_mfma_f32_16x16x32_bf16(ah[i], bmh[j], accM[i][j], 0, 0, 0);
                accM[i][j] = __builtin_amdgcn_mfma_f32_16x16x32_bf16(ah[i], bml[j], accM[i][j], 0, 0, 0);
                accM[i][j] = __builtin_amdgcn_mfma_f32_16x16x32_bf16(al[i], bmh[j], accM[i][j], 0, 0, 0);
                accP[i][j] = __builtin_amdgcn_mfma_f32_16x16x32_bf16(ah[i], bph[j], accP[i][j], 0, 0, 0);
                accP[i][j] = __builtin_amdgcn_mfma_f32_16x16x32_bf16(ah[i], bpl[j], accP[i][j], 0, 0, 0);
                accP[i][j] = __builtin_amdgcn_mfma_f32_16x16x32_bf16(al[i], bph[j], accP[i][j], 0, 0, 0);
            }
        __syncthreads();
    }

    // ---- epilogue: nonlinearity in place, then 2-pass LDS transpose (hi, lo) ----
    const int ccol = lane & 15;
    const int rbase = (lane >> 4) * 4;
    const int b_local = m0 >> 12;
    const int t00blk = m0 & (T_ - 1);
    const size_t specoff = (size_t)b_local * SE_E;

    // transform acc in place: accM := re, accP := im
    #pragma unroll
    for (int j = 0; j < 2; ++j) {
        int f = f0 + wc * 32 + j * 16 + ccol;
        bool live = (f < FREQ);
        float bm = live ? bias[f] : 0.f;
        float bp = live ? bias[FREQ + f] : 0.f;
        #pragma unroll
        for (int i = 0; i < 4; ++i)
            #pragma unroll
            for (int r = 0; r < 4; ++r) {
                float re = 0.f, im = 0.f;
                if (live) {
                    float mag = fminf(__expf(accM[i][j][r] + bm), CLAMP_MAXV);
                    float phv = accP[i][j][r] + bp;
                    float sp, cp; sincosf(phv, &sp, &cp);
                    re = mag * cp; im = mag * sp;
                }
                accM[i][j][r] = re; accP[i][j][r] = im;
            }
    }

    const int row0 = tid >> 3;     // 0..31
    const int c8 = (tid & 7) * 8;  // ushort chunk within 64
    #pragma unroll
    for (int pass = 0; pass < 2; ++pass) {
        #pragma unroll
        for (int j = 0; j < 2; ++j) {
            int u = wc * 32 + j * 16 + ccol;     // 0..63 within f-tile
            int par = u & 1;                     // 0 -> SE, 1 -> SO
            int kl = u & ~1;                     // kappa within tile (even)
            #pragma unroll
            for (int i = 0; i < 4; ++i) {
                #pragma unroll
                for (int r = 0; r < 4; ++r) {
                    float re = accM[i][j][r], im = accP[i][j][r];
                    ushort rv, iv;
                    if (pass == 0) {
                        rv = f2bf(re); iv = f2bf(im);
                    } else {
                        ushort rh = f2bf(re), ih = f2bf(im);
                        rv = f2bf(re - bf2f(rh)); iv = f2bf(im - bf2f(ih));
                    }
                    int tl = wr * 64 + i * 16 + rbase + r;
                    *reinterpret_cast<ushort2*>(&SH[par * 9216 + tl * 72 + kl]) =
                        make_ushort2(rv, iv);
                }
            }
        }
        __syncthreads();
        ushort* d0 = (pass ? SEl : SEh) + specoff;
        ushort* d1 = (pass ? SOl : SOh) + specoff;
        #pragma unroll
        for (int q2 = 0; q2 < 4; ++q2) {
            int row = q2 * 32 + row0;
            bf16x8 v0 = *reinterpret_cast<const bf16x8*>(&SH[row * 72 + c8]);
            bf16x8 v1 = *reinterpret_cast<const bf16x8*>(&SH[9216 + row * 72 + c8]);
            *reinterpret_cast<bf16x8*>(&d0[(size_t)(t00blk + row) * KE + f0 + c8]) = v0;
            *reinterpret_cast<bf16x8*>(&d1[(size_t)(t00blk + row) * KE + f0 + c8]) = v1;
        }
        if (pass == 0) __syncthreads();
    }
}

// ---------------- stage 1 GEMM (MFMA): EO[b][t][n''] = basis . spec  ----------------
// grid: (32 t-tiles, 8 n-tiles, bcount); block 256 (4 waves 2x2). Tile 128 n x 128 t, K=576.
// x-dim = t so the 4 same-parity readers of a spec t-panel share an XCD (32 % 8 == 0).
__global__ __launch_bounds__(256) void gemm_eo_mfma(
    const ushort* __restrict__ Abh, const ushort* __restrict__ Abl,
    const ushort* __restrict__ SEh, const ushort* __restrict__ SEl,
    const ushort* __restrict__ SOh, const ushort* __restrict__ SOl,
    float* __restrict__ EO)
{
    __shared__ __attribute__((aligned(16))) ushort sAh[128 * 32];
    __shared__ __attribute__((aligned(16))) ushort sAl[128 * 32];
    __shared__ __attribute__((aligned(16))) ushort sBh[128 * 32];
    __shared__ __attribute__((aligned(16))) ushort sBl[128 * 32];
    const int tid = threadIdx.x;
    const int lane = tid & 63;
    const int w = tid >> 6;
    const int wr = w >> 1, wc = w & 1;
    const int t0 = blockIdx.x * 128;
    const int n0 = blockIdx.y * 128;
    const int b_local = blockIdx.z;

    const ushort* Bsh = ((n0 < 512) ? SEh : SOh) + (size_t)b_local * SE_E;
    const ushort* Bsl = ((n0 < 512) ? SEl : SOl) + (size_t)b_local * SE_E;

    const int srow = tid >> 2;
    const int ssel = ((tid & 3) ^ ((tid >> 3) & 3)) * 8;
    const int arow = lane & 15;
    const int kch  = (((lane >> 4) ^ ((arow >> 1) & 3))) * 8;

    f32x4 acc[4][4] = {};
    char* pAh = (char*)sAh; char* pAl = (char*)sAl;
    char* pBh = (char*)sBh; char* pBl = (char*)sBl;

    for (int k0 = 0; k0 < KE; k0 += 32) {
        #pragma unroll
        for (int q = 0; q < 2; ++q) {
            size_t ao = (size_t)(n0 + q * 64 + srow) * KE + k0 + ssel;
            GLOAD_LDS16(Abh + ao, pAh + q * 4096 + w * 1024);
            GLOAD_LDS16(Abl + ao, pAl + q * 4096 + w * 1024);
            size_t bo = (size_t)(t0 + q * 64 + srow) * KE + k0 + ssel;
            GLOAD_LDS16(Bsh + bo, pBh + q * 4096 + w * 1024);
            GLOAD_LDS16(Bsl + bo, pBl + q * 4096 + w * 1024);
        }
        __syncthreads();
        bf16x8 ah[4], al[4], bh[4], bl[4];
        #pragma unroll
        for (int i = 0; i < 4; ++i) {
            int r = (wr * 64 + i * 16 + arow) * 32 + kch;
            ah[i] = *reinterpret_cast<const bf16x8*>(&sAh[r]);
            al[i] = *reinterpret_cast<const bf16x8*>(&sAl[r]);
        }
        #pragma unroll
        for (int j = 0; j < 4; ++j) {
            int r = (wc * 64 + j * 16 + arow) * 32 + kch;
            bh[j] = *reinterpret_cast<const bf16x8*>(&sBh[r]);
            bl[j] = *reinterpret_cast<const bf16x8*>(&sBl[r]);
        }
        #pragma unroll
        for (int i = 0; i < 4; ++i)
            #pragma unroll
            for (int j = 0; j < 4; ++j) {
                acc[i][j] = __builtin_amdgcn_mfma_f32_16x16x32_bf16(ah[i], bh[j], acc[i][j], 0, 0, 0);
                acc[i][j] = __builtin_amdgcn_mfma_f32_16x16x32_bf16(ah[i], bl[j], acc[i][j], 0, 0, 0);
                acc[i][j] = __builtin_amdgcn_mfma_f32_16x16x32_bf16(al[i], bh[j], acc[i][j], 0, 0, 0);
            }
        __syncthreads();
    }

    // epilogue: C row = n'', col = t; EO[b][t][n''] float4 stores
    const int ccol = lane & 15;
    const int rbase = (lane >> 4) * 4;
    float* eob = EO + (size_t)b_local * EO_E;
    #pragma unroll
    for (int i = 0; i < 4; ++i) {
        int nb = n0 + wr * 64 + i * 16 + rbase;
        #pragma unroll
        for (int j = 0; j < 4; ++j) {
            int t = t0 + wc * 64 + j * 16 + ccol;
            *reinterpret_cast<float4*>(&eob[(size_t)t * NFFT + nb]) =
                make_float4(acc[i][j][0], acc[i][j][1], acc[i][j][2], acc[i][j][3]);
        }
    }
}

// ---------------- gather: window * butterfly * OLA / env -> out ----------------
__global__ void gather_kernel(const float* __restrict__ EO,
                              const float* __restrict__ window,
                              float* __restrict__ out, int b0, int bcount) {
    int o = blockIdx.x * 256 + threadIdx.x;
    int s = o + PAD;
    int m = s >> 8, p = s & 255;
    float env = 1e-11f;
    float wv[4]; int tv[4]; int np[4]; float sg[4];
    #pragma unroll
    for (int j = 0; j < 4; ++j) {
        int t = m - j;
        bool ok = (t >= 0) && (t < T_);
        tv[j] = ok ? t : 0;
        np[j] = p + 256 * (j & 1);
        sg[j] = (j < 2) ? 1.f : -1.f;
        float ww = ok ? window[p + 256 * j] : 0.f;
        wv[j] = ww;
        env += ww * ww;
    }
    float inv = 1.0f / env;
    for (int bl = 0; bl < bcount; ++bl) {
        const float* eo = EO + (size_t)bl * EO_E;
        float y = 0.f;
        #pragma unroll
        for (int j = 0; j < 4; ++j) {
            const float* row = eo + (size_t)tv[j] * NFFT;
            float e = row[np[j]];
            float od = row[512 + np[j]];
            y = fmaf(wv[j], fmaf(sg[j], od, e), y);
        }
        out[(size_t)(b0 + bl) * OUTB + o] = y * inv;
    }
}

// ---------------- launch ----------------
extern "C" void kernel_launch(void* const* d_in, const int* in_sizes, int n_in,
                              void* d_out, int out_size, void* d_ws, size_t ws_size,
                              hipStream_t stream) {
    const float* x      = (const float*)d_in[0];
    const float* W      = (const float*)d_in[1];
    const float* bias   = (const float*)d_in[2];
    const float* window = (const float*)d_in[3];
    float* out = (float*)d_out;

    const size_t Ae  = (size_t)NFFT * KE;        //   589,824
    const size_t We  = (size_t)NW * H_;          //   294,912
    const size_t xeb = (size_t)T_ * H_;          // 2,097,152 per batch

    // bcount: largest that fits. Layout: [A|W|spec(4 bufs)|x(h,l)] with EO aliased
    // over the x region (x dead before gemm_eo writes EO; stream order makes it safe).
    int bcount = B_;
    for (;;) {
        size_t prefix = (2 * Ae + 4 * We + 4 * (size_t)bcount * SE_E) * sizeof(ushort);
        size_t tail = (size_t)bcount * EO_E * sizeof(float);
        if (prefix + tail <= ws_size || bcount == 1) break;
        bcount >>= 1;
    }

    ushort* Abh = (ushort*)d_ws;
    ushort* Abl = Abh + Ae;
    ushort* Wmh = Abl + Ae;
    ushort* Wml = Wmh + We;
    ushort* Wph = Wml + We;
    ushort* Wpl = Wph + We;
    ushort* SEh = Wpl + We;
    ushort* SEl = SEh + (size_t)bcount * SE_E;
    ushort* SOh = SEl + (size_t)bcount * SE_E;
    ushort* SOl = SOh + (size_t)bcount * SE_E;
    ushort* xhb = SOl + (size_t)bcount * SE_E;
    ushort* xlb = xhb + (size_t)bcount * xeb;
    float*  EO  = (float*)xhb;                    // aliases x region (+extends past it)

    basis_kernel<<<(NFFT * KE) / 256, 256, 0, stream>>>(Abh, Abl);
    prepw_kernel<<<(NW * H_ + 255) / 256, 256, 0, stream>>>(W, Wmh, Wml, Wph, Wpl);

    for (int b0 = 0; b0 < B_; b0 += bcount) {
        convx_kernel<<<(int)((size_t)bcount * xeb / 4 / 256), 256, 0, stream>>>(x, xhb, xlb, b0);
        dim3 ga(bcount * 32, 9);
        gemm_a_mfma<<<ga, 256, 0, stream>>>(xhb, xlb, Wmh, Wml, Wph, Wpl, bias,
                                            SEh, SEl, SOh, SOl);
        dim3 ge(32, 8, bcount);
        gemm_eo_mfma<<<ge, 256, 0, stream>>>(Abh, Abl, SEh, SEl, SOh, SOl, EO);
        gather_kernel<<<OUTB / 256, 256, 0, stream>>>(EO, window, out, b0, bcount);
    }
}